// Round 6
// baseline (727.026 us; speedup 1.0000x reference)
//
#include <hip/hip_runtime.h>
#include <hip/hip_bf16.h>
#include <math.h>

// Problem constants
#define Bb 4
#define Nn 4096
#define Hh 16
#define DHh 64
#define Mm 266
#define Dd 1024
#define BHh (Bb*Hh)

#define DN_SCALE 0.35355339059327373f   // 64^-0.25
#define RATIO 0.06131393394849658f      // 266^-0.5
#define EPS_FAVOR 1e-4f
#define EPS_LN 1e-5f

typedef __attribute__((ext_vector_type(8))) short frag_t;   // 8 x bf16
typedef __attribute__((ext_vector_type(4))) short sh4;      // 4 x bf16
typedef __attribute__((ext_vector_type(4))) float f32x4;

__device__ __forceinline__ ushort f2bf(float f) {
    unsigned u = __float_as_uint(f);
    return (ushort)((u + 0x7FFFu + ((u >> 16) & 1u)) >> 16);
}
__device__ __forceinline__ float bf2f(ushort h) {
    return __uint_as_float(((unsigned)h) << 16);
}
__device__ __forceinline__ unsigned fenc(float f) {
    unsigned u = __float_as_uint(f);
    return (u & 0x80000000u) ? ~u : (u | 0x80000000u);
}
__device__ __forceinline__ float fdec(unsigned e) {
    unsigned u = (e & 0x80000000u) ? (e ^ 0x80000000u) : ~e;
    return __uint_as_float(u);
}
__device__ __forceinline__ void gld16(const void* g, void* l) {
    __builtin_amdgcn_global_load_lds((const __attribute__((address_space(1))) unsigned int*)g,
                                     (__attribute__((address_space(3))) unsigned int*)l, 16, 0, 0);
}

// ---------------------------------------------------------------------------
// prep: x fp32 -> bf16
// ---------------------------------------------------------------------------
__global__ __launch_bounds__(256) void conv_x_kernel(const float* __restrict__ x,
                                                     ushort* __restrict__ xb) {
    size_t i = ((size_t)blockIdx.x * 256 + threadIdx.x) * 8;
    float4 f0 = *(const float4*)(x + i);
    float4 f1 = *(const float4*)(x + i + 4);
    uint4 o;
    o.x = (unsigned)f2bf(f0.x) | ((unsigned)f2bf(f0.y) << 16);
    o.y = (unsigned)f2bf(f0.z) | ((unsigned)f2bf(f0.w) << 16);
    o.z = (unsigned)f2bf(f1.x) | ((unsigned)f2bf(f1.y) << 16);
    o.w = (unsigned)f2bf(f1.z) | ((unsigned)f2bf(f1.w) << 16);
    *(uint4*)(xb + i) = o;
}

// prep: W[k][n] fp32 -> WT[n][k] bf16 (K-contiguous for the B^T GEMM)
__global__ __launch_bounds__(256) void conv_wt_kernel(
    const float* __restrict__ Wq, const float* __restrict__ Wk,
    const float* __restrict__ Wv, const float* __restrict__ Wo,
    ushort* __restrict__ Tq, ushort* __restrict__ Tk,
    ushort* __restrict__ Tv, ushort* __restrict__ To) {
    const int z = blockIdx.z;
    const float* W = z == 0 ? Wq : z == 1 ? Wk : z == 2 ? Wv : Wo;
    ushort* WT = z == 0 ? Tq : z == 1 ? Tk : z == 2 ? Tv : To;
    __shared__ float tls[64][65];
    const int tid = threadIdx.x;
    const int n0 = blockIdx.x * 64, k0 = blockIdx.y * 64;
    const int r = tid >> 2, seg = tid & 3;
#pragma unroll
    for (int i = 0; i < 4; ++i) {
        float4 f = *(const float4*)(W + (size_t)(k0 + r) * 1024 + n0 + seg * 16 + i * 4);
        tls[r][seg * 16 + i * 4 + 0] = f.x;
        tls[r][seg * 16 + i * 4 + 1] = f.y;
        tls[r][seg * 16 + i * 4 + 2] = f.z;
        tls[r][seg * 16 + i * 4 + 3] = f.w;
    }
    __syncthreads();
    const int nl = tid >> 2;
#pragma unroll
    for (int i = 0; i < 16; ++i)
        WT[(size_t)(n0 + nl) * 1024 + k0 + seg * 16 + i] = f2bf(tls[seg * 16 + i][nl]);
}

// prep: proj fp32 [266][64] -> bf16 hi/lo [320][128], zero-padded rows
__global__ __launch_bounds__(256) void conv_proj_kernel(const float* __restrict__ proj,
                                                        ushort* __restrict__ pb) {
    const int idx = blockIdx.x * 256 + threadIdx.x;   // 320*64 = 20480
    const int m = idx >> 6, k = idx & 63;
    float v = (m < Mm) ? proj[m * 64 + k] : 0.f;
    ushort hi = f2bf(v);
    float lo = v - bf2f(hi);
    pb[m * 128 + k] = hi;
    pb[m * 128 + 64 + k] = f2bf(lo);
}

// prep: diag[bh*4096+n] = 0.5 * sum_k kb[n][k]^2
__global__ __launch_bounds__(256) void diag_kernel(const ushort* __restrict__ kb,
                                                   float* __restrict__ dg) {
    const size_t i = (size_t)blockIdx.x * 256 + threadIdx.x;
    const ushort* p = kb + i * 64;
    float s = 0.f;
#pragma unroll
    for (int seg = 0; seg < 8; ++seg) {
        frag_t a = *(const frag_t*)(p + seg * 8);
#pragma unroll
        for (int j = 0; j < 8; ++j) { float f = bf2f((ushort)a[j]); s += f * f; }
    }
    dg[i] = 0.5f * s;
}

// prep: ctx fp32 [bh][m][64] -> ctxT hi/lo bf16 [bh][64 d][320 hi | 320 lo]
__global__ __launch_bounds__(256) void ctx2bt_kernel(const float* __restrict__ ctx,
                                                     ushort* __restrict__ cT) {
    const int mc = blockIdx.x;       // 0..4
    const int bh = blockIdx.y;
    const int tid = threadIdx.x;
    __shared__ float tls[64][65];
    const int r = tid >> 2, cs = tid & 3;
    const int gm = mc * 64 + r;
#pragma unroll
    for (int i = 0; i < 4; ++i) {
        float4 f = {0.f, 0.f, 0.f, 0.f};
        if (gm < Mm) f = *(const float4*)(ctx + ((size_t)bh * Mm + gm) * 64 + cs * 16 + i * 4);
        tls[r][cs * 16 + i * 4 + 0] = f.x;
        tls[r][cs * 16 + i * 4 + 1] = f.y;
        tls[r][cs * 16 + i * 4 + 2] = f.z;
        tls[r][cs * 16 + i * 4 + 3] = f.w;
    }
    __syncthreads();
    const int d = tid >> 2, ms = tid & 3;
    unsigned hi[8], lo[8];
#pragma unroll
    for (int j = 0; j < 8; ++j) {
        float v0 = tls[ms * 16 + j * 2][d];
        float v1 = tls[ms * 16 + j * 2 + 1][d];
        ushort h0 = f2bf(v0), h1 = f2bf(v1);
        ushort l0 = f2bf(v0 - bf2f(h0)), l1 = f2bf(v1 - bf2f(h1));
        hi[j] = (unsigned)h0 | ((unsigned)h1 << 16);
        lo[j] = (unsigned)l0 | ((unsigned)l1 << 16);
    }
    size_t base = (size_t)bh * 40960 + (size_t)d * 640 + mc * 64 + ms * 16;
    uint4 a = {hi[0], hi[1], hi[2], hi[3]};
    uint4 b = {hi[4], hi[5], hi[6], hi[7]};
    uint4 c = {lo[0], lo[1], lo[2], lo[3]};
    uint4 e = {lo[4], lo[5], lo[6], lo[7]};
    *(uint4*)(cT + base) = a;
    *(uint4*)(cT + base + 8) = b;
    *(uint4*)(cT + base + 320) = c;
    *(uint4*)(cT + base + 328) = e;
}

// ---------------------------------------------------------------------------
// 256x256 pipelined bf16 GEMM, 64 KiB static LDS (4 half-slot ring, BK=32).
// 8 waves (2Mx4N). Counted vmcnt (never 0 in steady state), raw barriers,
// XOR-swizzled LDS, setprio around the 32-MFMA cluster.
// mode 0: head-major bf16 out (z 0,1 scaled; z==2 writes transposed vT)
// mode 1: fp32 + bias + residual
// ---------------------------------------------------------------------------
__global__ __launch_bounds__(512, 2) void gemm256(
    const ushort* __restrict__ A,
    const ushort* __restrict__ W0, const ushort* __restrict__ W1, const ushort* __restrict__ W2,
    ushort* __restrict__ o0, ushort* __restrict__ o1, ushort* __restrict__ o2,
    const float* __restrict__ bo, const float* __restrict__ xres, float* __restrict__ yres,
    int mode)
{
    __shared__ ushort smem[32768];   // 4 half-slots x (A 4096 | B 4096) ushorts
    const int tid = threadIdx.x;
    const int lane = tid & 63, w = tid >> 6;
    const int q = lane >> 4, m16 = lane & 15;
    const int wm = w >> 2, wn = w & 3;
    const int row0 = blockIdx.x * 256, col0 = blockIdx.y * 256;
    const int z = blockIdx.z;
    const ushort* WT = (mode == 0) ? (z == 0 ? W0 : z == 1 ? W1 : W2) : W0;

    // staging: 512 thr x 16B = one 128-row x 32-k half (A or B) per gld16
    const int srow = tid >> 2, sseg = tid & 3;
    const int ksw = (sseg ^ ((srow >> 1) & 3)) * 8;   // pre-swizzled SOURCE k-chunk
    const int dst = tid * 8;                          // linear LDS dest
    const int sq  = (q ^ ((m16 >> 1) & 3)) * 8;      // swizzled READ k-chunk

#define STG(T_) do {                                                          \
        int s0_ = (2 * (T_)) & 3, s1_ = (2 * (T_) + 1) & 3;                   \
        gld16(A  + (size_t)(row0 + srow) * 1024 + (T_) * 32 + ksw,            \
              smem + s0_ * 8192 + dst);                                       \
        gld16(WT + (size_t)(col0 + srow) * 1024 + (T_) * 32 + ksw,            \
              smem + s0_ * 8192 + 4096 + dst);                                \
        gld16(A  + (size_t)(row0 + 128 + srow) * 1024 + (T_) * 32 + ksw,      \
              smem + s1_ * 8192 + dst);                                       \
        gld16(WT + (size_t)(col0 + 128 + srow) * 1024 + (T_) * 32 + ksw,      \
              smem + s1_ * 8192 + 4096 + dst);                                \
    } while (0)

    f32x4 acc[8][4];
#pragma unroll
    for (int i = 0; i < 8; ++i)
#pragma unroll
        for (int j = 0; j < 4; ++j) acc[i][j] = (f32x4){0.f, 0.f, 0.f, 0.f};

    STG(0);
    STG(1);

    for (int kt = 0; kt < 32; ++kt) {
        // tile kt's 4 loads are the oldest; tile kt+1's 4 may stay in flight
        if (kt < 31) { asm volatile("s_waitcnt vmcnt(4)" ::: "memory"); }
        else         { asm volatile("s_waitcnt vmcnt(0)" ::: "memory"); }
        __builtin_amdgcn_sched_barrier(0);
        __builtin_amdgcn_s_barrier();
        __builtin_amdgcn_sched_barrier(0);

        const ushort* As_ = smem + (((2 * kt + wm) & 3) * 8192);
        const ushort* Bs_ = smem + (((2 * kt + (wn >> 1)) & 3) * 8192) + 4096;
        frag_t af[8], bf[4];
#pragma unroll
        for (int i = 0; i < 8; ++i)
            af[i] = *(const frag_t*)&As_[(i * 16 + m16) * 32 + sq];
#pragma unroll
        for (int j = 0; j < 4; ++j)
            bf[j] = *(const frag_t*)&Bs_[((wn & 1) * 64 + j * 16 + m16) * 32 + sq];

        asm volatile("s_waitcnt lgkmcnt(0)" ::: "memory");
        __builtin_amdgcn_sched_barrier(0);
        __builtin_amdgcn_s_barrier();        // all waves' reads retired
        __builtin_amdgcn_sched_barrier(0);

        if (kt + 2 < 32) STG(kt + 2);        // overwrites slots just read - safe
        __builtin_amdgcn_sched_barrier(0);

        __builtin_amdgcn_s_setprio(1);
#pragma unroll
        for (int i = 0; i < 8; ++i)
#pragma unroll
            for (int j = 0; j < 4; ++j)
                acc[i][j] = __builtin_amdgcn_mfma_f32_16x16x32_bf16(af[i], bf[j], acc[i][j], 0, 0, 0);
        __builtin_amdgcn_s_setprio(0);
        __builtin_amdgcn_sched_barrier(0);
    }
#undef STG

    const int b = row0 >> 12;   // 256-row tile sits inside one batch
    if (mode == 0) {
        if (z == 2) {
            // direct transposed write: vT[((b*16+h)*64+dh)*4096 + n], 8B per lane
#pragma unroll
            for (int i = 0; i < 8; ++i)
#pragma unroll
                for (int j = 0; j < 4; ++j) {
                    int col = col0 + wn * 64 + j * 16 + m16;
                    size_t rowbase = ((size_t)((b << 4) + (col >> 6)) * 64 + (col & 63)) * 4096;
                    int n = (row0 & 4095) + wm * 128 + i * 16 + q * 4;
                    sh4 pk;
#pragma unroll
                    for (int r = 0; r < 4; ++r) pk[r] = (short)f2bf(acc[i][j][r]);
                    *(sh4*)(o2 + rowbase + n) = pk;
                }
        } else {
            ushort* outp = (z == 0) ? o0 : o1;
            // LDS bounce in 4 chunks of 64 rows -> coalesced 16B head-major stores
#pragma unroll
            for (int c = 0; c < 4; ++c) {
                __builtin_amdgcn_s_barrier();
                if (wm == (c >> 1)) {
#pragma unroll
                    for (int i2 = 0; i2 < 4; ++i2) {
                        int i = (c & 1) * 4 + i2;
#pragma unroll
                        for (int j = 0; j < 4; ++j)
#pragma unroll
                            for (int r = 0; r < 4; ++r)
                                smem[(i2 * 16 + q * 4 + r) * 264 + wn * 64 + j * 16 + m16] =
                                    f2bf(acc[i][j][r] * DN_SCALE);
                    }
                }
                __builtin_amdgcn_s_barrier();
#pragma unroll
                for (int it = 0; it < 4; ++it) {
                    int idx = it * 512 + tid;
                    int lr = idx >> 5, ch = idx & 31;
                    frag_t v = *(const frag_t*)&smem[lr * 264 + ch * 8];
                    int n = (row0 & 4095) + c * 64 + lr;
                    int h = (col0 >> 6) + (ch >> 3);
                    int dh = (ch & 7) * 8;
                    *(frag_t*)(outp + ((size_t)((b << 4) + h) * 4096 + n) * 64 + dh) = v;
                }
            }
        }
    } else {
#pragma unroll
        for (int i = 0; i < 8; ++i)
#pragma unroll
            for (int j = 0; j < 4; ++j)
#pragma unroll
                for (int r = 0; r < 4; ++r) {
                    int row = row0 + wm * 128 + i * 16 + q * 4 + r;
                    int col = col0 + wn * 64 + j * 16 + m16;
                    size_t off = (size_t)row * 1024 + col;
                    yres[off] = acc[i][j][r] + bo[col] + xres[off];
                }
    }
}

// ---------------------------------------------------------------------------
// k-stab via MFMA, 256 rows/block (hi-only; stab cancels analytically except
// the 1e-4 EPS term).  grid: (Nn/256, BH), block 256 (4 waves x 64 rows)
// ---------------------------------------------------------------------------
__global__ __launch_bounds__(256) void kstab_mfma_kernel(
    const ushort* __restrict__ kb, const ushort* __restrict__ pb,
    unsigned* __restrict__ stab_enc)
{
    const int n0 = blockIdx.x * 256;
    const int bh = blockIdx.y;
    const int tid = threadIdx.x;
    const int lane = tid & 63, w = tid >> 6;
    const int q = lane >> 4, m16 = lane & 15;

    __shared__ ushort ks_s[256 * 72];
    __shared__ ushort pj_s[64 * 72];

#pragma unroll
    for (int t = 0; t < 8; ++t) {
        int idx = tid + t * 256;
        int r = idx >> 3, s = idx & 7;
        *(frag_t*)&ks_s[r * 72 + s * 8] =
            *(const frag_t*)(kb + ((size_t)bh * Nn + n0 + r) * 64 + s * 8);
    }
    __syncthreads();

    frag_t aq[4][2];
#pragma unroll
    for (int g = 0; g < 4; ++g)
#pragma unroll
        for (int s = 0; s < 2; ++s)
            aq[g][s] = *(const frag_t*)&ks_s[(w * 64 + g * 16 + m16) * 72 + s * 32 + q * 8];

    float mx = -3.0e38f;
#pragma unroll
    for (int mc = 0; mc < 5; ++mc) {
        __syncthreads();
#pragma unroll
        for (int t = 0; t < 2; ++t) {
            int idx = tid + t * 256;
            int r = idx >> 3, cc = idx & 7;   // hi half only
            *(frag_t*)&pj_s[r * 72 + cc * 8] =
                *(const frag_t*)(pb + ((size_t)mc * 64 + r) * 128 + cc * 8);
        }
        __syncthreads();
#pragma unroll
        for (int tm = 0; tm < 4; ++tm) {
            const int t = mc * 4 + tm;
            if (t > 16) continue;
            frag_t bh0 = *(const frag_t*)&pj_s[(tm * 16 + m16) * 72 + q * 8];
            frag_t bh1 = *(const frag_t*)&pj_s[(tm * 16 + m16) * 72 + 32 + q * 8];
            bool v = (t < 16) || (m16 < 10);
#pragma unroll
            for (int g = 0; g < 4; ++g) {
                f32x4 sa = (f32x4){0.f, 0.f, 0.f, 0.f};
                sa = __builtin_amdgcn_mfma_f32_16x16x32_bf16(aq[g][0], bh0, sa, 0, 0, 0);
                sa = __builtin_amdgcn_mfma_f32_16x16x32_bf16(aq[g][1], bh1, sa, 0, 0, 0);
                if (v) {
#pragma unroll
                    for (int r = 0; r < 4; ++r) mx = fmaxf(mx, sa[r]);
                }
            }
        }
    }
    mx = fmaxf(mx, __shfl_xor(mx, 1));
    mx = fmaxf(mx, __shfl_xor(mx, 2));
    mx = fmaxf(mx, __shfl_xor(mx, 4));
    mx = fmaxf(mx, __shfl_xor(mx, 8));
    mx = fmaxf(mx, __shfl_xor(mx, 16));
    mx = fmaxf(mx, __shfl_xor(mx, 32));
    if (lane == 0) atomicMax(stab_enc + bh, fenc(mx));
}

// ---------------------------------------------------------------------------
// ctx via MFMA (unchanged, verified)
// ---------------------------------------------------------------------------
__global__ __launch_bounds__(256) void ctx_mfma_kernel(
    const ushort* __restrict__ kb, const ushort* __restrict__ vT,
    const ushort* __restrict__ pb, const float* __restrict__ diagk,
    const unsigned* __restrict__ stab_enc,
    float* __restrict__ ctx, float* __restrict__ ksum)
{
    const int m0 = blockIdx.x * 64;
    const int nb = blockIdx.y;
    const int bh = blockIdx.z;
    const int tid = threadIdx.x;
    const int lane = tid & 63, w = tid >> 6;
    const int q = lane >> 4, m16 = lane & 15;
    const float kst = fdec(stab_enc[bh]);

    __shared__ ushort ks_s[32 * 72];
    __shared__ ushort pj_s[64 * 136];
    __shared__ ushort kf_s[64 * 40];
    __shared__ ushort vt_s[64 * 40];
    __shared__ float  diag_s[32];

    for (int u = tid; u < 1024; u += 256) {
        int r = u >> 4, c = (u & 15) * 8;
        *(frag_t*)&pj_s[r * 136 + c] = *(const frag_t*)(pb + (size_t)(m0 + r) * 128 + c);
    }

    f32x4 acc_c[4];
#pragma unroll
    for (int j = 0; j < 4; ++j) acc_c[j] = (f32x4){0.f, 0.f, 0.f, 0.f};
    float ksacc[2] = {0.f, 0.f};

    const int tn  = w & 1;
    const int tmb = (w >> 1) * 2;

    const int srow_k = tid >> 3, sseg_k = tid & 7;
    const int srow_v = tid >> 2, sseg_v = tid & 3;
    const size_t kbase = ((size_t)bh * Nn + nb * 1024 + srow_k) * 64 + sseg_k * 8;
    const size_t vbase = ((size_t)bh * 64 + srow_v) * Nn + nb * 1024 + sseg_v * 8;
    const float* dgp = diagk + (size_t)bh * Nn + nb * 1024;

    frag_t kreg = *(const frag_t*)(kb + kbase);
    frag_t vreg = *(const frag_t*)(vT + vbase);
    float4 dreg;
    if (tid < 8) dreg = *(const float4*)(dgp + tid * 4);

    for (int t = 0; t < 32; ++t) {
        __syncthreads();
        *(frag_t*)&ks_s[srow_k * 72 + sseg_k * 8] = kreg;
        *(frag_t*)&vt_s[srow_v * 40 + sseg_v * 8] = vreg;
        if (tid < 8) *(float4*)&diag_s[tid * 4] = dreg;
        __syncthreads();
        if (t < 31) {
            kreg = *(const frag_t*)(kb + kbase + (size_t)(t + 1) * 2048);
            vreg = *(const frag_t*)(vT + vbase + (size_t)(t + 1) * 32);
            if (tid < 8) dreg = *(const float4*)(dgp + (t + 1) * 32 + tid * 4);
        }

        f32x4 sa[2];
        sa[0] = (f32x4){0.f, 0.f, 0.f, 0.f};
        sa[1] = (f32x4){0.f, 0.f, 0.f, 0.f};
#pragma unroll
        for (int s = 0; s < 2; ++s) {
            frag_t a = *(const frag_t*)&ks_s[(tn * 16 + m16) * 72 + s * 32 + q * 8];
#pragma unroll
            for (int jj = 0; jj < 2; ++jj) {
                const ushort* prow = &pj_s[((tmb + jj) * 16 + m16) * 136 + s * 32 + q * 8];
                frag_t bhi = *(const frag_t*)prow;
                frag_t blo = *(const frag_t*)(prow + 64);
                sa[jj] = __builtin_amdgcn_mfma_f32_16x16x32_bf16(a, bhi, sa[jj], 0, 0, 0);
                sa[jj] = __builtin_amdgcn_mfma_f32_16x16x32_bf16(a, blo, sa[jj], 0, 0, 0);
            }
        }

#pragma unroll
        for (int jj = 0; jj < 2; ++jj) {
            int m_l = (tmb + jj) * 16 + m16;
            bool valid = (m0 + m_l) < Mm;
            sh4 pk;
            float vsum = 0.f;
#pragma unroll
            for (int r = 0; r < 4; ++r) {
                int n_l = tn * 16 + q * 4 + r;
                float val = valid ? RATIO * (__expf(sa[jj][r] - diag_s[n_l] - kst) + EPS_FAVOR) : 0.f;
                ushort hb = f2bf(val);
                pk[r] = (short)hb;
                vsum += bf2f(hb);
            }
            ksacc[jj] += vsum;
            *(sh4*)&kf_s[m_l * 40 + tn * 16 + q * 4] = pk;
        }
        __syncthreads();

        {
            frag_t a = *(const frag_t*)&kf_s[(w * 16 + m16) * 40 + q * 8];
#pragma unroll
            for (int j = 0; j < 4; ++j) {
                frag_t b = *(const frag_t*)&vt_s[(j * 16 + m16) * 40 + q * 8];
                acc_c[j] = __builtin_amdgcn_mfma_f32_16x16x32_bf16(a, b, acc_c[j], 0, 0, 0);
            }
        }
    }

#pragma unroll
    for (int j = 0; j < 4; ++j)
#pragma unroll
        for (int r = 0; r < 4; ++r) {
            int m = m0 + w * 16 + q * 4 + r;
            if (m < Mm)
                atomicAdd(&ctx[((size_t)bh * Mm + m) * 64 + j * 16 + m16], acc_c[j][r]);
        }
#pragma unroll
    for (int jj = 0; jj < 2; ++jj) {
        float v = ksacc[jj];
        v += __shfl_xor(v, 16);
        v += __shfl_xor(v, 32);
        int m = m0 + (tmb + jj) * 16 + m16;
        if (q == 0 && m < Mm) atomicAdd(&ksum[(size_t)bh * Mm + m], v);
    }
}

// ---------------------------------------------------------------------------
// q-side via MFMA v2: B-operands (proj, ctxT) read DIRECTLY from global
// (L2-resident, line-coalesced via the 4 q-lanes). No staging, 2 barriers.
// LDS 52.7 KB -> 3 blocks/CU. qf_s is per-wave (rows w*16..w*16+15).
// grid: (Nn/64, BH), block 256
// ---------------------------------------------------------------------------
__global__ __launch_bounds__(256, 3) void qout_mfma_kernel(
    const ushort* __restrict__ qb, const ushort* __restrict__ pb,
    const ushort* __restrict__ cT, const float* __restrict__ ksum,
    ushort* __restrict__ attnb)
{
    const int n0 = blockIdx.x * 64;
    const int bh = blockIdx.y;
    const int b = bh >> 4, h = bh & 15;
    const int tid = threadIdx.x;
    const int lane = tid & 63, w = tid >> 6;
    const int q = lane >> 4, m16 = lane & 15;

    __shared__ ushort qs_s[64 * 72];     //  9.2 KB
    __shared__ ushort qf_s[64 * 328];    // 42.0 KB (per-wave 16-row segments)
    __shared__ float  diag_s[64];
    __shared__ float  ksum_s[320];

    // stage Q tile + ksum
#pragma unroll
    for (int t = 0; t < 2; ++t) {
        int idx = tid + t * 256;
        int r = idx >> 3, s = idx & 7;
        *(frag_t*)&qs_s[r * 72 + s * 8] =
            *(const frag_t*)(qb + ((size_t)bh * Nn + n0 + r) * 64 + s * 8);
    }
    for (int m = tid; m < 320; m += 256)
        ksum_s[m] = (m < Mm) ? ksum[(size_t)bh * Mm + m] : 0.f;
    __syncthreads();
    if (tid < 64) {
        float s = 0.f;
#pragma unroll 8
        for (int k = 0; k < 64; ++k) { float f = bf2f(qs_s[tid * 72 + k]); s += f * f; }
        diag_s[tid] = 0.5f * s;
    }
    __syncthreads();                       // diag visible to all waves

    frag_t aq[2];
#pragma unroll
    for (int s = 0; s < 2; ++s)
        aq[s] = *(const frag_t*)&qs_s[(w * 16 + m16) * 72 + s * 32 + q * 8];

    // ---- feature GEMM: S[16 rows][320 m], B direct from global pb ----
    f32x4 sA[20];
#pragma unroll
    for (int t = 0; t < 20; ++t) sA[t] = (f32x4){0.f, 0.f, 0.f, 0.f};

#pragma unroll
    for (int tm = 0; tm < 20; ++tm) {
#pragma unroll
        for (int s = 0; s < 2; ++s) {
            const ushort* pr = pb + (size_t)(tm * 16 + m16) * 128 + s * 32 + q * 8;
            frag_t bhi = *(const frag_t*)pr;
            frag_t blo = *(const frag_t*)(pr + 64);
            sA[tm] = __builtin_amdgcn_mfma_f32_16x16x32_bf16(aq[s], bhi, sA[tm], 0, 0, 0);
            sA[tm] = __builtin_amdgcn_mfma_f32_16x16x32_bf16(aq[s], blo, sA[tm], 0, 0, 0);
        }
    }

    // ---- row stats: stab max over valid m (cols in 16-lane group) ----
    float mx[4] = {-3.0e38f, -3.0e38f, -3.0e38f, -3.0e38f};
#pragma unroll
    for (int t = 0; t < 17; ++t) {
        bool v = (t < 16) || (m16 < 10);
        if (v) {
#pragma unroll
            for (int r = 0; r < 4; ++r) mx[r] = fmaxf(mx[r], sA[t][r]);
        }
    }
#pragma unroll
    for (int r = 0; r < 4; ++r) {
        float v = mx[r];
        v = fmaxf(v, __shfl_xor(v, 1));
        v = fmaxf(v, __shfl_xor(v, 2));
        v = fmaxf(v, __shfl_xor(v, 4));
        v = fmaxf(v, __shfl_xor(v, 8));
        mx[r] = v;
    }
    float dg[4];
#pragma unroll
    for (int r = 0; r < 4; ++r) dg[r] = diag_s[w * 16 + q * 4 + r];

    // ---- exp, ksum dot, qf -> LDS (bf16, own-wave rows) ----
    float ds[4] = {0.f, 0.f, 0.f, 0.f};
#pragma unroll
    for (int t = 0; t < 20; ++t) {
        int m = t * 16 + m16;
        bool v = m < Mm;
        float ksm = ksum_s[m];
#pragma unroll
        for (int r = 0; r < 4; ++r) {
            ushort hb = 0;
            float val = 0.f;
            if (v) {
                hb = f2bf(RATIO * (__expf(sA[t][r] - dg[r] - mx[r]) + EPS_FAVOR));
                val = bf2f(hb);
            }
            ds[r] += val * ksm;
            qf_s[(w * 16 + q * 4 + r) * 328 + m] = hb;
        }
    }
#pragma unroll
    for (int r = 0; r < 4; ++r) {
        float v = ds[r];
        v += __shfl_xor(v, 1);
        v += __shfl_xor(v, 2);
        v += __shfl_xor(v, 4);
        v += __shfl_xor(v, 8);
        ds[r] = 1.0f / v;
    }

    // ---- PV GEMM: out[16 rows][64 d] = qf @ ctxT^T, B direct from global ----
    // qf_s rows w*16.. written and read by the SAME wave: no barrier needed.
    f32x4 oA[4];
#pragma unroll
    for (int dt = 0; dt < 4; ++dt) oA[dt] = (f32x4){0.f, 0.f, 0.f, 0.f};

    const ushort* cbase = cT + (size_t)bh * 40960;
#pragma unroll
    for (int mc = 0; mc < 5; ++mc) {
#pragma unroll
        for (int s = 0; s < 2; ++s) {
            frag_t a = *(const frag_t*)&qf_s[(w * 16 + m16) * 328 + mc * 64 + s * 32 + q * 8];
#pragma unroll
            for (int dt = 0; dt < 4; ++dt) {
                const ushort* pr = cbase + (size_t)(dt * 16 + m16) * 640 + mc * 64 + s * 32 + q * 8;
                frag_t bhi = *(const frag_t*)pr;
                frag_t blo = *(const frag_t*)(pr + 320);
                oA[dt] = __builtin_amdgcn_mfma_f32_16x16x32_bf16(a, bhi, oA[dt], 0, 0, 0);
                oA[dt] = __builtin_amdgcn_mfma_f32_16x16x32_bf16(a, blo, oA[dt], 0, 0, 0);
            }
        }
    }

    // ---- epilogue: * dinv, store bf16 ----
#pragma unroll
    for (int dt = 0; dt < 4; ++dt)
#pragma unroll
        for (int r = 0; r < 4; ++r) {
            int n = n0 + w * 16 + q * 4 + r;
            attnb[((size_t)(b * Nn + n)) * Dd + h * 64 + dt * 16 + m16] =
                f2bf(oA[dt][r] * ds[r]);
        }
}

// ---------------------------------------------------------------------------
// LayerNorm: one block per row of 1024
// ---------------------------------------------------------------------------
__global__ __launch_bounds__(256) void ln_kernel(
    const float* __restrict__ y, const float* __restrict__ gamma,
    const float* __restrict__ beta, float* __restrict__ out)
{
    const int row = blockIdx.x;
    const int tid = threadIdx.x;
    float4 v = *(const float4*)(y + (size_t)row * Dd + tid * 4);
    float s = v.x + v.y + v.z + v.w;
    float q = v.x * v.x + v.y * v.y + v.z * v.z + v.w * v.w;
    __shared__ float rs[256], rq[256];
    rs[tid] = s; rq[tid] = q;
    __syncthreads();
    for (int off = 128; off > 0; off >>= 1) {
        if (tid < off) { rs[tid] += rs[tid + off]; rq[tid] += rq[tid + off]; }
        __syncthreads();
    }
    float mu = rs[0] * (1.0f / Dd);
    float var = rq[0] * (1.0f / Dd) - mu * mu;
    float rstd = rsqrtf(var + EPS_LN);
    float4 gm = *(const float4*)(gamma + tid * 4);
    float4 bt = *(const float4*)(beta + tid * 4);
    float4 o;
    o.x = (v.x - mu) * rstd * gm.x + bt.x;
    o.y = (v.y - mu) * rstd * gm.y + bt.y;
    o.z = (v.z - mu) * rstd * gm.z + bt.z;
    o.w = (v.w - mu) * rstd * gm.w + bt.w;
    *(float4*)(out + (size_t)row * Dd + tid * 4) = o;
}

// ---------------------------------------------------------------------------
extern "C" void kernel_launch(void* const* d_in, const int* in_sizes, int n_in,
                              void* d_out, int out_size, void* d_ws, size_t ws_size,
                              hipStream_t stream) {
    const float* x     = (const float*)d_in[0];
    const float* Wq    = (const float*)d_in[1];
    const float* Wk    = (const float*)d_in[2];
    const float* Wv    = (const float*)d_in[3];
    const float* Wo    = (const float*)d_in[4];
    const float* bo    = (const float*)d_in[5];
    const float* proj  = (const float*)d_in[6];
    const float* gamma = (const float*)d_in[7];
    const float* beta  = (const float*)d_in[8];
    float* out = (float*)d_out;

    const size_t TS = 16777216;           // tokens(16384) * 1024
    ushort* xb  = (ushort*)d_ws;          // x bf16; reused as attnb after QKV gemm
    ushort* qb  = xb + TS;
    ushort* kb  = qb + TS;
    ushort* vb  = kb + TS;                // holds vT [bh][64][4096] (gemm z==2 writes)
    ushort* WTq = vb + TS;
    ushort* WTk = WTq + 1048576;
    ushort* WTv = WTk + 1048576;
    ushort* WTo = WTv + 1048576;
    float*  ctx  = (float*)(WTo + 1048576);         // BH*M*64 fp32
    float*  ksum = ctx + (size_t)BHh * Mm * DHh;    // BH*M
    unsigned* stab = (unsigned*)(ksum + (size_t)BHh * Mm);
    ushort* attnb = xb;                   // token-major bf16 attn (after gemm consumed xb)
    float*  yres  = (float*)qb;           // fp32, overlays qb+kb after qout
    ushort* vT     = vb;                  // [bh][64][4096] bf16, direct from gemm z==2
    float*  diagk  = (float*)WTq;         // 1 MB in the 2 MB WTq slot (after gemm)
    ushort* projb2 = WTk;                 // 80 KB in the 2 MB WTk slot (after gemm)
    ushort* ctxT   = vb;                  // [bh][64][640] bf16 hi|lo (after ctx consumed vT)

    hipMemsetAsync(ctx, 0, (size_t)BHh * Mm * DHh * sizeof(float), stream);
    hipMemsetAsync(ksum, 0, (size_t)BHh * Mm * sizeof(float), stream);
    hipMemsetAsync(stab, 0, BHh * sizeof(unsigned), stream);

    conv_x_kernel<<<8192, 256, 0, stream>>>(x, xb);
    conv_wt_kernel<<<dim3(16, 16, 4), 256, 0, stream>>>(Wq, Wk, Wv, Wo, WTq, WTk, WTv, WTo);

    gemm256<<<dim3(64, 4, 3), 512, 0, stream>>>(xb, WTq, WTk, WTv, qb, kb, vT,
                                                nullptr, nullptr, nullptr, 0);

    diag_kernel<<<1024, 256, 0, stream>>>(kb, diagk);
    conv_proj_kernel<<<80, 256, 0, stream>>>(proj, projb2);

    kstab_mfma_kernel<<<dim3(Nn / 256, BHh), 256, 0, stream>>>(kb, projb2, stab);

    ctx_mfma_kernel<<<dim3(5, 4, BHh), 256, 0, stream>>>(kb, vT, projb2, diagk, stab,
                                                         ctx, ksum);

    ctx2bt_kernel<<<dim3(5, BHh), 256, 0, stream>>>(ctx, ctxT);

    qout_mfma_kernel<<<dim3(Nn / 64, BHh), 256, 0, stream>>>(qb, projb2, ctxT, ksum, attnb);

    gemm256<<<dim3(64, 4, 1), 512, 0, stream>>>(attnb, WTo, nullptr, nullptr,
                                                nullptr, nullptr, nullptr, bo, x, yres, 1);
    ln_kernel<<<16384, 256, 0, stream>>>(yres, gamma, beta, out);
}

// Round 7
// 572.993 us; speedup vs baseline: 1.2688x; 1.2688x over previous
//
#include <hip/hip_runtime.h>
#include <hip/hip_bf16.h>
#include <math.h>

// Problem constants
#define Bb 4
#define Nn 4096
#define Hh 16
#define DHh 64
#define Mm 266
#define Dd 1024
#define BHh (Bb*Hh)

#define DN_SCALE 0.35355339059327373f   // 64^-0.25
#define RATIO 0.06131393394849658f      // 266^-0.5
#define EPS_FAVOR 1e-4f
#define EPS_LN 1e-5f

typedef __attribute__((ext_vector_type(8))) short frag_t;   // 8 x bf16
typedef __attribute__((ext_vector_type(4))) short sh4;      // 4 x bf16
typedef __attribute__((ext_vector_type(4))) float f32x4;

__device__ __forceinline__ ushort f2bf(float f) {
    unsigned u = __float_as_uint(f);
    return (ushort)((u + 0x7FFFu + ((u >> 16) & 1u)) >> 16);
}
__device__ __forceinline__ float bf2f(ushort h) {
    return __uint_as_float(((unsigned)h) << 16);
}
__device__ __forceinline__ unsigned fenc(float f) {
    unsigned u = __float_as_uint(f);
    return (u & 0x80000000u) ? ~u : (u | 0x80000000u);
}
__device__ __forceinline__ float fdec(unsigned e) {
    unsigned u = (e & 0x80000000u) ? (e ^ 0x80000000u) : ~e;
    return __uint_as_float(u);
}
__device__ __forceinline__ void gld16(const void* g, void* l) {
    __builtin_amdgcn_global_load_lds((const __attribute__((address_space(1))) unsigned int*)g,
                                     (__attribute__((address_space(3))) unsigned int*)l, 16, 0, 0);
}

// raw barrier with LDS drain only (global prefetches stay in flight)
#define SYNC_LDS() do {                                             \
        asm volatile("s_waitcnt lgkmcnt(0)" ::: "memory");          \
        __builtin_amdgcn_sched_barrier(0);                          \
        __builtin_amdgcn_s_barrier();                               \
        __builtin_amdgcn_sched_barrier(0);                          \
    } while (0)

// ---------------------------------------------------------------------------
// prep: x fp32 -> bf16
// ---------------------------------------------------------------------------
__global__ __launch_bounds__(256) void conv_x_kernel(const float* __restrict__ x,
                                                     ushort* __restrict__ xb) {
    size_t i = ((size_t)blockIdx.x * 256 + threadIdx.x) * 8;
    float4 f0 = *(const float4*)(x + i);
    float4 f1 = *(const float4*)(x + i + 4);
    uint4 o;
    o.x = (unsigned)f2bf(f0.x) | ((unsigned)f2bf(f0.y) << 16);
    o.y = (unsigned)f2bf(f0.z) | ((unsigned)f2bf(f0.w) << 16);
    o.z = (unsigned)f2bf(f1.x) | ((unsigned)f2bf(f1.y) << 16);
    o.w = (unsigned)f2bf(f1.z) | ((unsigned)f2bf(f1.w) << 16);
    *(uint4*)(xb + i) = o;
}

// prep: W[k][n] fp32 -> WT[n][k] bf16 (K-contiguous for the B^T GEMM)
__global__ __launch_bounds__(256) void conv_wt_kernel(
    const float* __restrict__ Wq, const float* __restrict__ Wk,
    const float* __restrict__ Wv, const float* __restrict__ Wo,
    ushort* __restrict__ Tq, ushort* __restrict__ Tk,
    ushort* __restrict__ Tv, ushort* __restrict__ To) {
    const int z = blockIdx.z;
    const float* W = z == 0 ? Wq : z == 1 ? Wk : z == 2 ? Wv : Wo;
    ushort* WT = z == 0 ? Tq : z == 1 ? Tk : z == 2 ? Tv : To;
    __shared__ float tls[64][65];
    const int tid = threadIdx.x;
    const int n0 = blockIdx.x * 64, k0 = blockIdx.y * 64;
    const int r = tid >> 2, seg = tid & 3;
#pragma unroll
    for (int i = 0; i < 4; ++i) {
        float4 f = *(const float4*)(W + (size_t)(k0 + r) * 1024 + n0 + seg * 16 + i * 4);
        tls[r][seg * 16 + i * 4 + 0] = f.x;
        tls[r][seg * 16 + i * 4 + 1] = f.y;
        tls[r][seg * 16 + i * 4 + 2] = f.z;
        tls[r][seg * 16 + i * 4 + 3] = f.w;
    }
    __syncthreads();
    const int nl = tid >> 2;
#pragma unroll
    for (int i = 0; i < 16; ++i)
        WT[(size_t)(n0 + nl) * 1024 + k0 + seg * 16 + i] = f2bf(tls[seg * 16 + i][nl]);
}

// prep: proj fp32 [266][64] -> bf16 hi/lo [320][128], zero-padded rows
__global__ __launch_bounds__(256) void conv_proj_kernel(const float* __restrict__ proj,
                                                        ushort* __restrict__ pb) {
    const int idx = blockIdx.x * 256 + threadIdx.x;   // 320*64 = 20480
    const int m = idx >> 6, k = idx & 63;
    float v = (m < Mm) ? proj[m * 64 + k] : 0.f;
    ushort hi = f2bf(v);
    float lo = v - bf2f(hi);
    pb[m * 128 + k] = hi;
    pb[m * 128 + 64 + k] = f2bf(lo);
}

// prep: diag[bh*4096+n] = 0.5 * sum_k kb[n][k]^2
__global__ __launch_bounds__(256) void diag_kernel(const ushort* __restrict__ kb,
                                                   float* __restrict__ dg) {
    const size_t i = (size_t)blockIdx.x * 256 + threadIdx.x;
    const ushort* p = kb + i * 64;
    float s = 0.f;
#pragma unroll
    for (int seg = 0; seg < 8; ++seg) {
        frag_t a = *(const frag_t*)(p + seg * 8);
#pragma unroll
        for (int j = 0; j < 8; ++j) { float f = bf2f((ushort)a[j]); s += f * f; }
    }
    dg[i] = 0.5f * s;
}

// prep: ctx fp32 [bh][m][64] -> ctxT hi/lo bf16 [bh][64 d][320 hi | 320 lo]
__global__ __launch_bounds__(256) void ctx2bt_kernel(const float* __restrict__ ctx,
                                                     ushort* __restrict__ cT) {
    const int mc = blockIdx.x;       // 0..4
    const int bh = blockIdx.y;
    const int tid = threadIdx.x;
    __shared__ float tls[64][65];
    const int r = tid >> 2, cs = tid & 3;
    const int gm = mc * 64 + r;
#pragma unroll
    for (int i = 0; i < 4; ++i) {
        float4 f = {0.f, 0.f, 0.f, 0.f};
        if (gm < Mm) f = *(const float4*)(ctx + ((size_t)bh * Mm + gm) * 64 + cs * 16 + i * 4);
        tls[r][cs * 16 + i * 4 + 0] = f.x;
        tls[r][cs * 16 + i * 4 + 1] = f.y;
        tls[r][cs * 16 + i * 4 + 2] = f.z;
        tls[r][cs * 16 + i * 4 + 3] = f.w;
    }
    __syncthreads();
    const int d = tid >> 2, ms = tid & 3;
    unsigned hi[8], lo[8];
#pragma unroll
    for (int j = 0; j < 8; ++j) {
        float v0 = tls[ms * 16 + j * 2][d];
        float v1 = tls[ms * 16 + j * 2 + 1][d];
        ushort h0 = f2bf(v0), h1 = f2bf(v1);
        ushort l0 = f2bf(v0 - bf2f(h0)), l1 = f2bf(v1 - bf2f(h1));
        hi[j] = (unsigned)h0 | ((unsigned)h1 << 16);
        lo[j] = (unsigned)l0 | ((unsigned)l1 << 16);
    }
    size_t base = (size_t)bh * 40960 + (size_t)d * 640 + mc * 64 + ms * 16;
    uint4 a = {hi[0], hi[1], hi[2], hi[3]};
    uint4 b = {hi[4], hi[5], hi[6], hi[7]};
    uint4 c = {lo[0], lo[1], lo[2], lo[3]};
    uint4 e = {lo[4], lo[5], lo[6], lo[7]};
    *(uint4*)(cT + base) = a;
    *(uint4*)(cT + base + 8) = b;
    *(uint4*)(cT + base + 320) = c;
    *(uint4*)(cT + base + 328) = e;
}

// ---------------------------------------------------------------------------
// 256x256 pipelined bf16 GEMM (verified R5)
// ---------------------------------------------------------------------------
__global__ __launch_bounds__(512, 2) void gemm256(
    const ushort* __restrict__ A,
    const ushort* __restrict__ W0, const ushort* __restrict__ W1, const ushort* __restrict__ W2,
    ushort* __restrict__ o0, ushort* __restrict__ o1, ushort* __restrict__ o2,
    const float* __restrict__ bo, const float* __restrict__ xres, float* __restrict__ yres,
    int mode)
{
    __shared__ ushort smem[32768];   // 4 half-slots x (A 4096 | B 4096) ushorts
    const int tid = threadIdx.x;
    const int lane = tid & 63, w = tid >> 6;
    const int q = lane >> 4, m16 = lane & 15;
    const int wm = w >> 2, wn = w & 3;
    const int row0 = blockIdx.x * 256, col0 = blockIdx.y * 256;
    const int z = blockIdx.z;
    const ushort* WT = (mode == 0) ? (z == 0 ? W0 : z == 1 ? W1 : W2) : W0;

    const int srow = tid >> 2, sseg = tid & 3;
    const int ksw = (sseg ^ ((srow >> 1) & 3)) * 8;
    const int dst = tid * 8;
    const int sq  = (q ^ ((m16 >> 1) & 3)) * 8;

#define STG(T_) do {                                                          \
        int s0_ = (2 * (T_)) & 3, s1_ = (2 * (T_) + 1) & 3;                   \
        gld16(A  + (size_t)(row0 + srow) * 1024 + (T_) * 32 + ksw,            \
              smem + s0_ * 8192 + dst);                                       \
        gld16(WT + (size_t)(col0 + srow) * 1024 + (T_) * 32 + ksw,            \
              smem + s0_ * 8192 + 4096 + dst);                                \
        gld16(A  + (size_t)(row0 + 128 + srow) * 1024 + (T_) * 32 + ksw,      \
              smem + s1_ * 8192 + dst);                                       \
        gld16(WT + (size_t)(col0 + 128 + srow) * 1024 + (T_) * 32 + ksw,      \
              smem + s1_ * 8192 + 4096 + dst);                                \
    } while (0)

    f32x4 acc[8][4];
#pragma unroll
    for (int i = 0; i < 8; ++i)
#pragma unroll
        for (int j = 0; j < 4; ++j) acc[i][j] = (f32x4){0.f, 0.f, 0.f, 0.f};

    STG(0);
    STG(1);

    for (int kt = 0; kt < 32; ++kt) {
        if (kt < 31) { asm volatile("s_waitcnt vmcnt(4)" ::: "memory"); }
        else         { asm volatile("s_waitcnt vmcnt(0)" ::: "memory"); }
        __builtin_amdgcn_sched_barrier(0);
        __builtin_amdgcn_s_barrier();
        __builtin_amdgcn_sched_barrier(0);

        const ushort* As_ = smem + (((2 * kt + wm) & 3) * 8192);
        const ushort* Bs_ = smem + (((2 * kt + (wn >> 1)) & 3) * 8192) + 4096;
        frag_t af[8], bf[4];
#pragma unroll
        for (int i = 0; i < 8; ++i)
            af[i] = *(const frag_t*)&As_[(i * 16 + m16) * 32 + sq];
#pragma unroll
        for (int j = 0; j < 4; ++j)
            bf[j] = *(const frag_t*)&Bs_[((wn & 1) * 64 + j * 16 + m16) * 32 + sq];

        asm volatile("s_waitcnt lgkmcnt(0)" ::: "memory");
        __builtin_amdgcn_sched_barrier(0);
        __builtin_amdgcn_s_barrier();
        __builtin_amdgcn_sched_barrier(0);

        if (kt + 2 < 32) STG(kt + 2);
        __builtin_amdgcn_sched_barrier(0);

        __builtin_amdgcn_s_setprio(1);
#pragma unroll
        for (int i = 0; i < 8; ++i)
#pragma unroll
            for (int j = 0; j < 4; ++j)
                acc[i][j] = __builtin_amdgcn_mfma_f32_16x16x32_bf16(af[i], bf[j], acc[i][j], 0, 0, 0);
        __builtin_amdgcn_s_setprio(0);
        __builtin_amdgcn_sched_barrier(0);
    }
#undef STG

    const int b = row0 >> 12;
    if (mode == 0) {
        if (z == 2) {
#pragma unroll
            for (int i = 0; i < 8; ++i)
#pragma unroll
                for (int j = 0; j < 4; ++j) {
                    int col = col0 + wn * 64 + j * 16 + m16;
                    size_t rowbase = ((size_t)((b << 4) + (col >> 6)) * 64 + (col & 63)) * 4096;
                    int n = (row0 & 4095) + wm * 128 + i * 16 + q * 4;
                    sh4 pk;
#pragma unroll
                    for (int r = 0; r < 4; ++r) pk[r] = (short)f2bf(acc[i][j][r]);
                    *(sh4*)(o2 + rowbase + n) = pk;
                }
        } else {
            ushort* outp = (z == 0) ? o0 : o1;
#pragma unroll
            for (int c = 0; c < 4; ++c) {
                __builtin_amdgcn_s_barrier();
                if (wm == (c >> 1)) {
#pragma unroll
                    for (int i2 = 0; i2 < 4; ++i2) {
                        int i = (c & 1) * 4 + i2;
#pragma unroll
                        for (int j = 0; j < 4; ++j)
#pragma unroll
                            for (int r = 0; r < 4; ++r)
                                smem[(i2 * 16 + q * 4 + r) * 264 + wn * 64 + j * 16 + m16] =
                                    f2bf(acc[i][j][r] * DN_SCALE);
                    }
                }
                __builtin_amdgcn_s_barrier();
#pragma unroll
                for (int it = 0; it < 4; ++it) {
                    int idx = it * 512 + tid;
                    int lr = idx >> 5, ch = idx & 31;
                    frag_t v = *(const frag_t*)&smem[lr * 264 + ch * 8];
                    int n = (row0 & 4095) + c * 64 + lr;
                    int h = (col0 >> 6) + (ch >> 3);
                    int dh = (ch & 7) * 8;
                    *(frag_t*)(outp + ((size_t)((b << 4) + h) * 4096 + n) * 64 + dh) = v;
                }
            }
        }
    } else {
#pragma unroll
        for (int i = 0; i < 8; ++i)
#pragma unroll
            for (int j = 0; j < 4; ++j)
#pragma unroll
                for (int r = 0; r < 4; ++r) {
                    int row = row0 + wm * 128 + i * 16 + q * 4 + r;
                    int col = col0 + wn * 64 + j * 16 + m16;
                    size_t off = (size_t)row * 1024 + col;
                    yres[off] = acc[i][j][r] + bo[col] + xres[off];
                }
    }
}

// ---------------------------------------------------------------------------
// k-stab via MFMA, 256 rows/block (verified R5)
// ---------------------------------------------------------------------------
__global__ __launch_bounds__(256) void kstab_mfma_kernel(
    const ushort* __restrict__ kb, const ushort* __restrict__ pb,
    unsigned* __restrict__ stab_enc)
{
    const int n0 = blockIdx.x * 256;
    const int bh = blockIdx.y;
    const int tid = threadIdx.x;
    const int lane = tid & 63, w = tid >> 6;
    const int q = lane >> 4, m16 = lane & 15;

    __shared__ ushort ks_s[256 * 72];
    __shared__ ushort pj_s[64 * 72];

#pragma unroll
    for (int t = 0; t < 8; ++t) {
        int idx = tid + t * 256;
        int r = idx >> 3, s = idx & 7;
        *(frag_t*)&ks_s[r * 72 + s * 8] =
            *(const frag_t*)(kb + ((size_t)bh * Nn + n0 + r) * 64 + s * 8);
    }
    __syncthreads();

    frag_t aq[4][2];
#pragma unroll
    for (int g = 0; g < 4; ++g)
#pragma unroll
        for (int s = 0; s < 2; ++s)
            aq[g][s] = *(const frag_t*)&ks_s[(w * 64 + g * 16 + m16) * 72 + s * 32 + q * 8];

    float mx = -3.0e38f;
#pragma unroll
    for (int mc = 0; mc < 5; ++mc) {
        __syncthreads();
#pragma unroll
        for (int t = 0; t < 2; ++t) {
            int idx = tid + t * 256;
            int r = idx >> 3, cc = idx & 7;   // hi half only
            *(frag_t*)&pj_s[r * 72 + cc * 8] =
                *(const frag_t*)(pb + ((size_t)mc * 64 + r) * 128 + cc * 8);
        }
        __syncthreads();
#pragma unroll
        for (int tm = 0; tm < 4; ++tm) {
            const int t = mc * 4 + tm;
            if (t > 16) continue;
            frag_t bh0 = *(const frag_t*)&pj_s[(tm * 16 + m16) * 72 + q * 8];
            frag_t bh1 = *(const frag_t*)&pj_s[(tm * 16 + m16) * 72 + 32 + q * 8];
            bool v = (t < 16) || (m16 < 10);
#pragma unroll
            for (int g = 0; g < 4; ++g) {
                f32x4 sa = (f32x4){0.f, 0.f, 0.f, 0.f};
                sa = __builtin_amdgcn_mfma_f32_16x16x32_bf16(aq[g][0], bh0, sa, 0, 0, 0);
                sa = __builtin_amdgcn_mfma_f32_16x16x32_bf16(aq[g][1], bh1, sa, 0, 0, 0);
                if (v) {
#pragma unroll
                    for (int r = 0; r < 4; ++r) mx = fmaxf(mx, sa[r]);
                }
            }
        }
    }
    mx = fmaxf(mx, __shfl_xor(mx, 1));
    mx = fmaxf(mx, __shfl_xor(mx, 2));
    mx = fmaxf(mx, __shfl_xor(mx, 4));
    mx = fmaxf(mx, __shfl_xor(mx, 8));
    mx = fmaxf(mx, __shfl_xor(mx, 16));
    mx = fmaxf(mx, __shfl_xor(mx, 32));
    if (lane == 0) atomicMax(stab_enc + bh, fenc(mx));
}

// ---------------------------------------------------------------------------
// ctx via MFMA (unchanged, verified)
// ---------------------------------------------------------------------------
__global__ __launch_bounds__(256) void ctx_mfma_kernel(
    const ushort* __restrict__ kb, const ushort* __restrict__ vT,
    const ushort* __restrict__ pb, const float* __restrict__ diagk,
    const unsigned* __restrict__ stab_enc,
    float* __restrict__ ctx, float* __restrict__ ksum)
{
    const int m0 = blockIdx.x * 64;
    const int nb = blockIdx.y;
    const int bh = blockIdx.z;
    const int tid = threadIdx.x;
    const int lane = tid & 63, w = tid >> 6;
    const int q = lane >> 4, m16 = lane & 15;
    const float kst = fdec(stab_enc[bh]);

    __shared__ ushort ks_s[32 * 72];
    __shared__ ushort pj_s[64 * 136];
    __shared__ ushort kf_s[64 * 40];
    __shared__ ushort vt_s[64 * 40];
    __shared__ float  diag_s[32];

    for (int u = tid; u < 1024; u += 256) {
        int r = u >> 4, c = (u & 15) * 8;
        *(frag_t*)&pj_s[r * 136 + c] = *(const frag_t*)(pb + (size_t)(m0 + r) * 128 + c);
    }

    f32x4 acc_c[4];
#pragma unroll
    for (int j = 0; j < 4; ++j) acc_c[j] = (f32x4){0.f, 0.f, 0.f, 0.f};
    float ksacc[2] = {0.f, 0.f};

    const int tn  = w & 1;
    const int tmb = (w >> 1) * 2;

    const int srow_k = tid >> 3, sseg_k = tid & 7;
    const int srow_v = tid >> 2, sseg_v = tid & 3;
    const size_t kbase = ((size_t)bh * Nn + nb * 1024 + srow_k) * 64 + sseg_k * 8;
    const size_t vbase = ((size_t)bh * 64 + srow_v) * Nn + nb * 1024 + sseg_v * 8;
    const float* dgp = diagk + (size_t)bh * Nn + nb * 1024;

    frag_t kreg = *(const frag_t*)(kb + kbase);
    frag_t vreg = *(const frag_t*)(vT + vbase);
    float4 dreg;
    if (tid < 8) dreg = *(const float4*)(dgp + tid * 4);

    for (int t = 0; t < 32; ++t) {
        __syncthreads();
        *(frag_t*)&ks_s[srow_k * 72 + sseg_k * 8] = kreg;
        *(frag_t*)&vt_s[srow_v * 40 + sseg_v * 8] = vreg;
        if (tid < 8) *(float4*)&diag_s[tid * 4] = dreg;
        __syncthreads();
        if (t < 31) {
            kreg = *(const frag_t*)(kb + kbase + (size_t)(t + 1) * 2048);
            vreg = *(const frag_t*)(vT + vbase + (size_t)(t + 1) * 32);
            if (tid < 8) dreg = *(const float4*)(dgp + (t + 1) * 32 + tid * 4);
        }

        f32x4 sa[2];
        sa[0] = (f32x4){0.f, 0.f, 0.f, 0.f};
        sa[1] = (f32x4){0.f, 0.f, 0.f, 0.f};
#pragma unroll
        for (int s = 0; s < 2; ++s) {
            frag_t a = *(const frag_t*)&ks_s[(tn * 16 + m16) * 72 + s * 32 + q * 8];
#pragma unroll
            for (int jj = 0; jj < 2; ++jj) {
                const ushort* prow = &pj_s[((tmb + jj) * 16 + m16) * 136 + s * 32 + q * 8];
                frag_t bhi = *(const frag_t*)prow;
                frag_t blo = *(const frag_t*)(prow + 64);
                sa[jj] = __builtin_amdgcn_mfma_f32_16x16x32_bf16(a, bhi, sa[jj], 0, 0, 0);
                sa[jj] = __builtin_amdgcn_mfma_f32_16x16x32_bf16(a, blo, sa[jj], 0, 0, 0);
            }
        }

#pragma unroll
        for (int jj = 0; jj < 2; ++jj) {
            int m_l = (tmb + jj) * 16 + m16;
            bool valid = (m0 + m_l) < Mm;
            sh4 pk;
            float vsum = 0.f;
#pragma unroll
            for (int r = 0; r < 4; ++r) {
                int n_l = tn * 16 + q * 4 + r;
                float val = valid ? RATIO * (__expf(sa[jj][r] - diag_s[n_l] - kst) + EPS_FAVOR) : 0.f;
                ushort hb = f2bf(val);
                pk[r] = (short)hb;
                vsum += bf2f(hb);
            }
            ksacc[jj] += vsum;
            *(sh4*)&kf_s[m_l * 40 + tn * 16 + q * 4] = pk;
        }
        __syncthreads();

        {
            frag_t a = *(const frag_t*)&kf_s[(w * 16 + m16) * 40 + q * 8];
#pragma unroll
            for (int j = 0; j < 4; ++j) {
                frag_t b = *(const frag_t*)&vt_s[(j * 16 + m16) * 40 + q * 8];
                acc_c[j] = __builtin_amdgcn_mfma_f32_16x16x32_bf16(a, b, acc_c[j], 0, 0, 0);
            }
        }
    }

#pragma unroll
    for (int j = 0; j < 4; ++j)
#pragma unroll
        for (int r = 0; r < 4; ++r) {
            int m = m0 + w * 16 + q * 4 + r;
            if (m < Mm)
                atomicAdd(&ctx[((size_t)bh * Mm + m) * 64 + j * 16 + m16], acc_c[j][r]);
        }
#pragma unroll
    for (int jj = 0; jj < 2; ++jj) {
        float v = ksacc[jj];
        v += __shfl_xor(v, 16);
        v += __shfl_xor(v, 32);
        int m = m0 + (tmb + jj) * 16 + m16;
        if (q == 0 && m < Mm) atomicAdd(&ksum[(size_t)bh * Mm + m], v);
    }
}

// ---------------------------------------------------------------------------
// q-side via MFMA v3: unified 10-chunk T14 pipeline.
// Chunks 0-4 = proj hi/lo, 5-9 = ctxT hi/lo, through a 2-slot padded LDS ring.
// Per iter: MFMA on chunk i (slot i&1) while chunk i+1 loads fly in regs;
// then ds_write chunk i+1 -> other slot, issue chunk i+2 loads, ONE raw
// barrier (LDS-drain only, global prefetch stays in flight).
// exp fused per-chunk into the PV loop (qf chunk buffer, per-wave rows).
// grid: (Nn/64, BH), block 256
// ---------------------------------------------------------------------------
__global__ __launch_bounds__(256, 3) void qout_mfma_kernel(
    const ushort* __restrict__ qb, const ushort* __restrict__ pb,
    const ushort* __restrict__ cT, const float* __restrict__ ksum,
    ushort* __restrict__ attnb)
{
    const int n0 = blockIdx.x * 64;
    const int bh = blockIdx.y;
    const int b = bh >> 4, h = bh & 15;
    const int tid = threadIdx.x;
    const int lane = tid & 63, w = tid >> 6;
    const int q = lane >> 4, m16 = lane & 15;

    __shared__ ushort qs_s[64 * 64];        //  8.0 KB (linear, gld16-staged)
    __shared__ ushort pj_s[2 * 64 * 136];   // 34.0 KB ring
    __shared__ ushort qf_s[64 * 72];        //  9.0 KB chunk buffer
    __shared__ float  diag_s[64];
    __shared__ float  ksum_s[320];

    const ushort* cbase = cT + (size_t)bh * 40960;

#define LOADCH(i_) {                                                              \
        for (int t_ = 0; t_ < 4; ++t_) {                                          \
            int idx_ = tid + t_ * 256, rr_ = idx_ >> 4, cc_ = idx_ & 15;          \
            g[t_] = ((i_) <= 4)                                                   \
                ? *(const frag_t*)(pb + (size_t)((i_) * 64 + rr_) * 128 + cc_ * 8)\
                : *(const frag_t*)(cbase + (size_t)rr_ * 640 + (cc_ >> 3) * 320   \
                                   + ((i_) - 5) * 64 + (cc_ & 7) * 8);            \
        } }
#define STORECH(i_) {                                                             \
        ushort* sl_ = pj_s + (((i_) & 1) * 8704);                                 \
        for (int t_ = 0; t_ < 4; ++t_) {                                          \
            int idx_ = tid + t_ * 256, rr_ = idx_ >> 4, cc_ = idx_ & 15;          \
            *(frag_t*)&sl_[rr_ * 136 + cc_ * 8] = g[t_];                          \
        } }

    // ksum (C loads; waited by compiler before its stores)
    for (int m = tid; m < 320; m += 256)
        ksum_s[m] = (m < Mm) ? ksum[(size_t)bh * Mm + m] : 0.f;

    // Q tile: linear gld16 copy (64 rows x 64 k = 8 KB)
    const ushort* qsrc = qb + ((size_t)bh * Nn + n0) * 64;
    gld16(qsrc + tid * 8,        (void*)(qs_s + tid * 8));
    gld16(qsrc + 2048 + tid * 8, (void*)(qs_s + 2048 + tid * 8));

    frag_t g[4];
    LOADCH(0);
    STORECH(0);                 // compiler inserts the vmcnt for g
    LOADCH(1);                  // chunk1 in flight across the prologue barrier
    asm volatile("s_waitcnt vmcnt(4)" ::: "memory");   // qs gld16 landed; chunk1 flying
    __builtin_amdgcn_sched_barrier(0);
    SYNC_LDS();

    if (tid < 64) {
        float s = 0.f;
#pragma unroll 8
        for (int k = 0; k < 64; ++k) { float f = bf2f(qs_s[tid * 64 + k]); s += f * f; }
        diag_s[tid] = 0.5f * s;
    }
    frag_t aq[2];
#pragma unroll
    for (int s = 0; s < 2; ++s)
        aq[s] = *(const frag_t*)&qs_s[(w * 16 + m16) * 64 + s * 32 + q * 8];
    SYNC_LDS();

    // ---- feature GEMM over chunks 0..4 ----
    f32x4 sA[20];
#pragma unroll
    for (int t = 0; t < 20; ++t) sA[t] = (f32x4){0.f, 0.f, 0.f, 0.f};

#pragma unroll
    for (int mc = 0; mc < 5; ++mc) {
        const ushort* sl = pj_s + ((mc & 1) * 8704);
        __builtin_amdgcn_s_setprio(1);
#pragma unroll
        for (int tm = 0; tm < 4; ++tm)
#pragma unroll
            for (int s = 0; s < 2; ++s) {
                const ushort* pr = &sl[(tm * 16 + m16) * 136 + s * 32 + q * 8];
                frag_t bhi = *(const frag_t*)pr;
                frag_t blo = *(const frag_t*)(pr + 64);
                sA[mc * 4 + tm] = __builtin_amdgcn_mfma_f32_16x16x32_bf16(aq[s], bhi, sA[mc * 4 + tm], 0, 0, 0);
                sA[mc * 4 + tm] = __builtin_amdgcn_mfma_f32_16x16x32_bf16(aq[s], blo, sA[mc * 4 + tm], 0, 0, 0);
            }
        __builtin_amdgcn_s_setprio(0);
        STORECH(mc + 1);                       // chunk mc+1 regs -> other slot
        LOADCH(mc + 2);                        // chunk mc+2 -> regs (in flight)
        SYNC_LDS();
    }

    // ---- row stats (register-only; ctxT chunks 5,6 flying underneath) ----
    float mx[4] = {-3.0e38f, -3.0e38f, -3.0e38f, -3.0e38f};
#pragma unroll
    for (int t = 0; t < 17; ++t) {
        bool v = (t < 16) || (m16 < 10);
        if (v) {
#pragma unroll
            for (int r = 0; r < 4; ++r) mx[r] = fmaxf(mx[r], sA[t][r]);
        }
    }
#pragma unroll
    for (int r = 0; r < 4; ++r) {
        float v = mx[r];
        v = fmaxf(v, __shfl_xor(v, 1));
        v = fmaxf(v, __shfl_xor(v, 2));
        v = fmaxf(v, __shfl_xor(v, 4));
        v = fmaxf(v, __shfl_xor(v, 8));
        mx[r] = v;
    }
    float dg[4];
#pragma unroll
    for (int r = 0; r < 4; ++r) dg[r] = diag_s[w * 16 + q * 4 + r];

    // ---- PV over chunks 5..9: exp chunk -> qf_s (own-wave rows) -> MFMA ----
    float ds[4] = {0.f, 0.f, 0.f, 0.f};
    f32x4 oA[4];
#pragma unroll
    for (int dt = 0; dt < 4; ++dt) oA[dt] = (f32x4){0.f, 0.f, 0.f, 0.f};

#pragma unroll
    for (int mc = 0; mc < 5; ++mc) {
#pragma unroll
        for (int tm = 0; tm < 4; ++tm) {
            int t = mc * 4 + tm;
            float ksm = ksum_s[t * 16 + m16];     // zero-padded m>=266
#pragma unroll
            for (int r = 0; r < 4; ++r) {
                ushort hb = f2bf(RATIO * (__expf(sA[t][r] - dg[r] - mx[r]) + EPS_FAVOR));
                ds[r] += bf2f(hb) * ksm;
                qf_s[(w * 16 + q * 4 + r) * 72 + tm * 16 + m16] = hb;
            }
        }
        const ushort* sl = pj_s + (((mc + 5) & 1) * 8704);
        __builtin_amdgcn_s_setprio(1);
#pragma unroll
        for (int s = 0; s < 2; ++s) {
            frag_t a = *(const frag_t*)&qf_s[(w * 16 + m16) * 72 + s * 32 + q * 8];
#pragma unroll
            for (int dt = 0; dt < 4; ++dt) {
                const ushort* pr = &sl[(dt * 16 + m16) * 136 + s * 32 + q * 8];
                frag_t bhi = *(const frag_t*)pr;
                frag_t blo = *(const frag_t*)(pr + 64);
                oA[dt] = __builtin_amdgcn_mfma_f32_16x16x32_bf16(a, bhi, oA[dt], 0, 0, 0);
                oA[dt] = __builtin_amdgcn_mfma_f32_16x16x32_bf16(a, blo, oA[dt], 0, 0, 0);
            }
        }
        __builtin_amdgcn_s_setprio(0);
        if (mc + 6 <= 9) STORECH(mc + 6);
        if (mc + 7 <= 9) LOADCH(mc + 7);
        SYNC_LDS();
    }
#undef LOADCH
#undef STORECH

    // ---- dinv + epilogue ----
#pragma unroll
    for (int r = 0; r < 4; ++r) {
        float v = ds[r];
        v += __shfl_xor(v, 1);
        v += __shfl_xor(v, 2);
        v += __shfl_xor(v, 4);
        v += __shfl_xor(v, 8);
        ds[r] = 1.0f / v;
    }
#pragma unroll
    for (int dt = 0; dt < 4; ++dt)
#pragma unroll
        for (int r = 0; r < 4; ++r) {
            int n = n0 + w * 16 + q * 4 + r;
            attnb[((size_t)(b * Nn + n)) * Dd + h * 64 + dt * 16 + m16] =
                f2bf(oA[dt][r] * ds[r]);
        }
}

// ---------------------------------------------------------------------------
// LayerNorm: one block per row of 1024
// ---------------------------------------------------------------------------
__global__ __launch_bounds__(256) void ln_kernel(
    const float* __restrict__ y, const float* __restrict__ gamma,
    const float* __restrict__ beta, float* __restrict__ out)
{
    const int row = blockIdx.x;
    const int tid = threadIdx.x;
    float4 v = *(const float4*)(y + (size_t)row * Dd + tid * 4);
    float s = v.x + v.y + v.z + v.w;
    float q = v.x * v.x + v.y * v.y + v.z * v.z + v.w * v.w;
    __shared__ float rs[256], rq[256];
    rs[tid] = s; rq[tid] = q;
    __syncthreads();
    for (int off = 128; off > 0; off >>= 1) {
        if (tid < off) { rs[tid] += rs[tid + off]; rq[tid] += rq[tid + off]; }
        __syncthreads();
    }
    float mu = rs[0] * (1.0f / Dd);
    float var = rq[0] * (1.0f / Dd) - mu * mu;
    float rstd = rsqrtf(var + EPS_LN);
    float4 gm = *(const float4*)(gamma + tid * 4);
    float4 bt = *(const float4*)(beta + tid * 4);
    float4 o;
    o.x = (v.x - mu) * rstd * gm.x + bt.x;
    o.y = (v.y - mu) * rstd * gm.y + bt.y;
    o.z = (v.z - mu) * rstd * gm.z + bt.z;
    o.w = (v.w - mu) * rstd * gm.w + bt.w;
    *(float4*)(out + (size_t)row * Dd + tid * 4) = o;
}

// ---------------------------------------------------------------------------
extern "C" void kernel_launch(void* const* d_in, const int* in_sizes, int n_in,
                              void* d_out, int out_size, void* d_ws, size_t ws_size,
                              hipStream_t stream) {
    const float* x     = (const float*)d_in[0];
    const float* Wq    = (const float*)d_in[1];
    const float* Wk    = (const float*)d_in[2];
    const float* Wv    = (const float*)d_in[3];
    const float* Wo    = (const float*)d_in[4];
    const float* bo    = (const float*)d_in[5];
    const float* proj  = (const float*)d_in[6];
    const float* gamma = (const float*)d_in[7];
    const float* beta  = (const float*)d_in[8];
    float* out = (float*)d_out;

    const size_t TS = 16777216;           // tokens(16384) * 1024
    ushort* xb  = (ushort*)d_ws;          // x bf16; reused as attnb after QKV gemm
    ushort* qb  = xb + TS;
    ushort* kb  = qb + TS;
    ushort* vb  = kb + TS;                // holds vT [bh][64][4096] (gemm z==2 writes)
    ushort* WTq = vb + TS;
    ushort* WTk = WTq + 1048576;
    ushort* WTv = WTk + 1048576;
    ushort* WTo = WTv + 1048576;
    float*  ctx  = (float*)(WTo + 1048576);         // BH*M*64 fp32
    float*  ksum = ctx + (size_t)BHh * Mm * DHh;    // BH*M
    unsigned* stab = (unsigned*)(ksum + (size_t)BHh * Mm);
    ushort* attnb = xb;                   // token-major bf16 attn (after gemm consumed xb)
    float*  yres  = (float*)qb;           // fp32, overlays qb+kb after qout
    ushort* vT     = vb;                  // [bh][64][4096] bf16, direct from gemm z==2
    float*  diagk  = (float*)WTq;         // 1 MB in the 2 MB WTq slot (after gemm)
    ushort* projb2 = WTk;                 // 80 KB in the 2 MB WTk slot (after gemm)
    ushort* ctxT   = vb;                  // [bh][64][640] bf16 hi|lo (after ctx consumed vT)

    hipMemsetAsync(ctx, 0, (size_t)BHh * Mm * DHh * sizeof(float), stream);
    hipMemsetAsync(ksum, 0, (size_t)BHh * Mm * sizeof(float), stream);
    hipMemsetAsync(stab, 0, BHh * sizeof(unsigned), stream);

    conv_x_kernel<<<8192, 256, 0, stream>>>(x, xb);
    conv_wt_kernel<<<dim3(16, 16, 4), 256, 0, stream>>>(Wq, Wk, Wv, Wo, WTq, WTk, WTv, WTo);

    gemm256<<<dim3(64, 4, 3), 512, 0, stream>>>(xb, WTq, WTk, WTv, qb, kb, vT,
                                                nullptr, nullptr, nullptr, 0);

    diag_kernel<<<1024, 256, 0, stream>>>(kb, diagk);
    conv_proj_kernel<<<80, 256, 0, stream>>>(proj, projb2);

    kstab_mfma_kernel<<<dim3(Nn / 256, BHh), 256, 0, stream>>>(kb, projb2, stab);

    ctx_mfma_kernel<<<dim3(5, 4, BHh), 256, 0, stream>>>(kb, vT, projb2, diagk, stab,
                                                         ctx, ksum);

    ctx2bt_kernel<<<dim3(5, BHh), 256, 0, stream>>>(ctx, ctxT);

    qout_mfma_kernel<<<dim3(Nn / 64, BHh), 256, 0, stream>>>(qb, projb2, ctxT, ksum, attnb);

    gemm256<<<dim3(64, 4, 1), 512, 0, stream>>>(attnb, WTo, nullptr, nullptr,
                                                nullptr, nullptr, nullptr, bo, x, yres, 1);
    ln_kernel<<<16384, 256, 0, stream>>>(yres, gamma, beta, out);
}

// Round 8
// 562.622 us; speedup vs baseline: 1.2922x; 1.0184x over previous
//
#include <hip/hip_runtime.h>
#include <hip/hip_bf16.h>
#include <math.h>

// Problem constants
#define Bb 4
#define Nn 4096
#define Hh 16
#define DHh 64
#define Mm 266
#define Dd 1024
#define BHh (Bb*Hh)

#define DN_SCALE 0.35355339059327373f   // 64^-0.25
#define RATIO 0.06131393394849658f      // 266^-0.5
#define EPS_FAVOR 1e-4f
#define EPS_LN 1e-5f

typedef __attribute__((ext_vector_type(8))) short frag_t;   // 8 x bf16
typedef __attribute__((ext_vector_type(4))) short sh4;      // 4 x bf16
typedef __attribute__((ext_vector_type(4))) float f32x4;

__device__ __forceinline__ ushort f2bf(float f) {
    unsigned u = __float_as_uint(f);
    return (ushort)((u + 0x7FFFu + ((u >> 16) & 1u)) >> 16);
}
__device__ __forceinline__ float bf2f(ushort h) {
    return __uint_as_float(((unsigned)h) << 16);
}
__device__ __forceinline__ unsigned fenc(float f) {
    unsigned u = __float_as_uint(f);
    return (u & 0x80000000u) ? ~u : (u | 0x80000000u);
}
__device__ __forceinline__ float fdec(unsigned e) {
    unsigned u = (e & 0x80000000u) ? (e ^ 0x80000000u) : ~e;
    return __uint_as_float(u);
}
__device__ __forceinline__ void gld16(const void* g, void* l) {
    __builtin_amdgcn_global_load_lds((const __attribute__((address_space(1))) unsigned int*)g,
                                     (__attribute__((address_space(3))) unsigned int*)l, 16, 0, 0);
}

// raw barrier with LDS drain only (global prefetches stay in flight)
#define SYNC_LDS() do {                                             \
        asm volatile("s_waitcnt lgkmcnt(0)" ::: "memory");          \
        __builtin_amdgcn_sched_barrier(0);                          \
        __builtin_amdgcn_s_barrier();                               \
        __builtin_amdgcn_sched_barrier(0);                          \
    } while (0)

// ---------------------------------------------------------------------------
// prep: x fp32 -> bf16
// ---------------------------------------------------------------------------
__global__ __launch_bounds__(256) void conv_x_kernel(const float* __restrict__ x,
                                                     ushort* __restrict__ xb) {
    size_t i = ((size_t)blockIdx.x * 256 + threadIdx.x) * 8;
    float4 f0 = *(const float4*)(x + i);
    float4 f1 = *(const float4*)(x + i + 4);
    uint4 o;
    o.x = (unsigned)f2bf(f0.x) | ((unsigned)f2bf(f0.y) << 16);
    o.y = (unsigned)f2bf(f0.z) | ((unsigned)f2bf(f0.w) << 16);
    o.z = (unsigned)f2bf(f1.x) | ((unsigned)f2bf(f1.y) << 16);
    o.w = (unsigned)f2bf(f1.z) | ((unsigned)f2bf(f1.w) << 16);
    *(uint4*)(xb + i) = o;
}

// prep: W[k][n] fp32 -> WT[n][k] bf16 (K-contiguous for the B^T GEMM)
__global__ __launch_bounds__(256) void conv_wt_kernel(
    const float* __restrict__ Wq, const float* __restrict__ Wk,
    const float* __restrict__ Wv, const float* __restrict__ Wo,
    ushort* __restrict__ Tq, ushort* __restrict__ Tk,
    ushort* __restrict__ Tv, ushort* __restrict__ To) {
    const int z = blockIdx.z;
    const float* W = z == 0 ? Wq : z == 1 ? Wk : z == 2 ? Wv : Wo;
    ushort* WT = z == 0 ? Tq : z == 1 ? Tk : z == 2 ? Tv : To;
    __shared__ float tls[64][65];
    const int tid = threadIdx.x;
    const int n0 = blockIdx.x * 64, k0 = blockIdx.y * 64;
    const int r = tid >> 2, seg = tid & 3;
#pragma unroll
    for (int i = 0; i < 4; ++i) {
        float4 f = *(const float4*)(W + (size_t)(k0 + r) * 1024 + n0 + seg * 16 + i * 4);
        tls[r][seg * 16 + i * 4 + 0] = f.x;
        tls[r][seg * 16 + i * 4 + 1] = f.y;
        tls[r][seg * 16 + i * 4 + 2] = f.z;
        tls[r][seg * 16 + i * 4 + 3] = f.w;
    }
    __syncthreads();
    const int nl = tid >> 2;
#pragma unroll
    for (int i = 0; i < 16; ++i)
        WT[(size_t)(n0 + nl) * 1024 + k0 + seg * 16 + i] = f2bf(tls[seg * 16 + i][nl]);
}

// prep: proj fp32 [266][64] -> bf16 hi/lo [320][128], zero-padded rows
__global__ __launch_bounds__(256) void conv_proj_kernel(const float* __restrict__ proj,
                                                        ushort* __restrict__ pb) {
    const int idx = blockIdx.x * 256 + threadIdx.x;   // 320*64 = 20480
    const int m = idx >> 6, k = idx & 63;
    float v = (m < Mm) ? proj[m * 64 + k] : 0.f;
    ushort hi = f2bf(v);
    float lo = v - bf2f(hi);
    pb[m * 128 + k] = hi;
    pb[m * 128 + 64 + k] = f2bf(lo);
}

// prep: diag[bh*4096+n] = 0.5 * sum_k kb[n][k]^2
__global__ __launch_bounds__(256) void diag_kernel(const ushort* __restrict__ kb,
                                                   float* __restrict__ dg) {
    const size_t i = (size_t)blockIdx.x * 256 + threadIdx.x;
    const ushort* p = kb + i * 64;
    float s = 0.f;
#pragma unroll
    for (int seg = 0; seg < 8; ++seg) {
        frag_t a = *(const frag_t*)(p + seg * 8);
#pragma unroll
        for (int j = 0; j < 8; ++j) { float f = bf2f((ushort)a[j]); s += f * f; }
    }
    dg[i] = 0.5f * s;
}

// prep: ctx fp32 [bh][m][64] -> ctxT hi/lo bf16 [bh][64 d][320 hi | 320 lo]
__global__ __launch_bounds__(256) void ctx2bt_kernel(const float* __restrict__ ctx,
                                                     ushort* __restrict__ cT) {
    const int mc = blockIdx.x;       // 0..4
    const int bh = blockIdx.y;
    const int tid = threadIdx.x;
    __shared__ float tls[64][65];
    const int r = tid >> 2, cs = tid & 3;
    const int gm = mc * 64 + r;
#pragma unroll
    for (int i = 0; i < 4; ++i) {
        float4 f = {0.f, 0.f, 0.f, 0.f};
        if (gm < Mm) f = *(const float4*)(ctx + ((size_t)bh * Mm + gm) * 64 + cs * 16 + i * 4);
        tls[r][cs * 16 + i * 4 + 0] = f.x;
        tls[r][cs * 16 + i * 4 + 1] = f.y;
        tls[r][cs * 16 + i * 4 + 2] = f.z;
        tls[r][cs * 16 + i * 4 + 3] = f.w;
    }
    __syncthreads();
    const int d = tid >> 2, ms = tid & 3;
    unsigned hi[8], lo[8];
#pragma unroll
    for (int j = 0; j < 8; ++j) {
        float v0 = tls[ms * 16 + j * 2][d];
        float v1 = tls[ms * 16 + j * 2 + 1][d];
        ushort h0 = f2bf(v0), h1 = f2bf(v1);
        ushort l0 = f2bf(v0 - bf2f(h0)), l1 = f2bf(v1 - bf2f(h1));
        hi[j] = (unsigned)h0 | ((unsigned)h1 << 16);
        lo[j] = (unsigned)l0 | ((unsigned)l1 << 16);
    }
    size_t base = (size_t)bh * 40960 + (size_t)d * 640 + mc * 64 + ms * 16;
    uint4 a = {hi[0], hi[1], hi[2], hi[3]};
    uint4 b = {hi[4], hi[5], hi[6], hi[7]};
    uint4 c = {lo[0], lo[1], lo[2], lo[3]};
    uint4 e = {lo[4], lo[5], lo[6], lo[7]};
    *(uint4*)(cT + base) = a;
    *(uint4*)(cT + base + 8) = b;
    *(uint4*)(cT + base + 320) = c;
    *(uint4*)(cT + base + 328) = e;
}

// ---------------------------------------------------------------------------
// 256x256 deep-ring bf16 GEMM, 128 KiB static LDS (8 half-slots = 4 K-tiles,
// BK=32). 8 waves (2Mx4N). ONE barrier per K-tile: STG(kt+3) targets tile
// kt-1's slots, whose ds_reads retired before this iteration's barrier.
// Counted vmcnt(8) steady-state (3-tile prefetch); compiler-scheduled
// lgkmcnt interleaves ds_read with MFMA. XOR-swizzled LDS (0 conflicts, R7).
// mode 0: head-major bf16 out (z 0,1 scaled; z==2 writes transposed vT)
// mode 1: fp32 + bias + residual
// ---------------------------------------------------------------------------
__global__ __launch_bounds__(512, 2) void gemm256(
    const ushort* __restrict__ A,
    const ushort* __restrict__ W0, const ushort* __restrict__ W1, const ushort* __restrict__ W2,
    ushort* __restrict__ o0, ushort* __restrict__ o1, ushort* __restrict__ o2,
    const float* __restrict__ bo, const float* __restrict__ xres, float* __restrict__ yres,
    int mode)
{
    __shared__ ushort smem[65536];   // 8 half-slots x (A 4096 | B 4096) ushorts = 128 KiB
    const int tid = threadIdx.x;
    const int lane = tid & 63, w = tid >> 6;
    const int q = lane >> 4, m16 = lane & 15;
    const int wm = w >> 2, wn = w & 3;
    const int row0 = blockIdx.x * 256, col0 = blockIdx.y * 256;
    const int z = blockIdx.z;
    const ushort* WT = (mode == 0) ? (z == 0 ? W0 : z == 1 ? W1 : W2) : W0;

    const int srow = tid >> 2, sseg = tid & 3;
    const int ksw = (sseg ^ ((srow >> 1) & 3)) * 8;   // pre-swizzled SOURCE k-chunk
    const int dst = tid * 8;                          // linear LDS dest
    const int sq  = (q ^ ((m16 >> 1) & 3)) * 8;      // swizzled READ k-chunk

#define STG(T_) do {                                                          \
        int s0_ = (2 * (T_)) & 7, s1_ = (2 * (T_) + 1) & 7;                   \
        gld16(A  + (size_t)(row0 + srow) * 1024 + (T_) * 32 + ksw,            \
              smem + s0_ * 8192 + dst);                                       \
        gld16(WT + (size_t)(col0 + srow) * 1024 + (T_) * 32 + ksw,            \
              smem + s0_ * 8192 + 4096 + dst);                                \
        gld16(A  + (size_t)(row0 + 128 + srow) * 1024 + (T_) * 32 + ksw,      \
              smem + s1_ * 8192 + dst);                                       \
        gld16(WT + (size_t)(col0 + 128 + srow) * 1024 + (T_) * 32 + ksw,      \
              smem + s1_ * 8192 + 4096 + dst);                                \
    } while (0)

    f32x4 acc[8][4];
#pragma unroll
    for (int i = 0; i < 8; ++i)
#pragma unroll
        for (int j = 0; j < 4; ++j) acc[i][j] = (f32x4){0.f, 0.f, 0.f, 0.f};

    STG(0);
    STG(1);
    STG(2);

    for (int kt = 0; kt < 32; ++kt) {
        // tile kt's 4 loads are the oldest of <=12 outstanding
        if (kt < 30)       { asm volatile("s_waitcnt vmcnt(8)" ::: "memory"); }
        else if (kt == 30) { asm volatile("s_waitcnt vmcnt(4)" ::: "memory"); }
        else               { asm volatile("s_waitcnt vmcnt(0)" ::: "memory"); }
        __builtin_amdgcn_sched_barrier(0);
        __builtin_amdgcn_s_barrier();       // all waves: tile kt staged AND
        __builtin_amdgcn_sched_barrier(0);  // tile kt-1 reads retired

        if (kt + 3 < 32) STG(kt + 3);       // overwrites tile kt-1's slots - safe

        const ushort* As_ = smem + (((2 * kt + wm) & 7) * 8192);
        const ushort* Bs_ = smem + (((2 * kt + (wn >> 1)) & 7) * 8192) + 4096;
        frag_t af[8], bf[4];
#pragma unroll
        for (int i = 0; i < 8; ++i)
            af[i] = *(const frag_t*)&As_[(i * 16 + m16) * 32 + sq];
#pragma unroll
        for (int j = 0; j < 4; ++j)
            bf[j] = *(const frag_t*)&Bs_[((wn & 1) * 64 + j * 16 + m16) * 32 + sq];

        // no drain, no second barrier: compiler emits counted lgkmcnt and
        // interleaves the MFMAs with the ds_reads.
        __builtin_amdgcn_s_setprio(1);
#pragma unroll
        for (int i = 0; i < 8; ++i)
#pragma unroll
            for (int j = 0; j < 4; ++j)
                acc[i][j] = __builtin_amdgcn_mfma_f32_16x16x32_bf16(af[i], bf[j], acc[i][j], 0, 0, 0);
        __builtin_amdgcn_s_setprio(0);
    }
#undef STG

    const int b = row0 >> 12;
    if (mode == 0) {
        if (z == 2) {
#pragma unroll
            for (int i = 0; i < 8; ++i)
#pragma unroll
                for (int j = 0; j < 4; ++j) {
                    int col = col0 + wn * 64 + j * 16 + m16;
                    size_t rowbase = ((size_t)((b << 4) + (col >> 6)) * 64 + (col & 63)) * 4096;
                    int n = (row0 & 4095) + wm * 128 + i * 16 + q * 4;
                    sh4 pk;
#pragma unroll
                    for (int r = 0; r < 4; ++r) pk[r] = (short)f2bf(acc[i][j][r]);
                    *(sh4*)(o2 + rowbase + n) = pk;
                }
        } else {
            ushort* outp = (z == 0) ? o0 : o1;
#pragma unroll
            for (int c = 0; c < 4; ++c) {
                __builtin_amdgcn_s_barrier();
                if (wm == (c >> 1)) {
#pragma unroll
                    for (int i2 = 0; i2 < 4; ++i2) {
                        int i = (c & 1) * 4 + i2;
#pragma unroll
                        for (int j = 0; j < 4; ++j)
#pragma unroll
                            for (int r = 0; r < 4; ++r)
                                smem[(i2 * 16 + q * 4 + r) * 264 + wn * 64 + j * 16 + m16] =
                                    f2bf(acc[i][j][r] * DN_SCALE);
                    }
                }
                __builtin_amdgcn_s_barrier();
#pragma unroll
                for (int it = 0; it < 4; ++it) {
                    int idx = it * 512 + tid;
                    int lr = idx >> 5, ch = idx & 31;
                    frag_t v = *(const frag_t*)&smem[lr * 264 + ch * 8];
                    int n = (row0 & 4095) + c * 64 + lr;
                    int h = (col0 >> 6) + (ch >> 3);
                    int dh = (ch & 7) * 8;
                    *(frag_t*)(outp + ((size_t)((b << 4) + h) * 4096 + n) * 64 + dh) = v;
                }
            }
        }
    } else {
#pragma unroll
        for (int i = 0; i < 8; ++i)
#pragma unroll
            for (int j = 0; j < 4; ++j)
#pragma unroll
                for (int r = 0; r < 4; ++r) {
                    int row = row0 + wm * 128 + i * 16 + q * 4 + r;
                    int col = col0 + wn * 64 + j * 16 + m16;
                    size_t off = (size_t)row * 1024 + col;
                    yres[off] = acc[i][j][r] + bo[col] + xres[off];
                }
    }
}

// ---------------------------------------------------------------------------
// k-stab via MFMA, 256 rows/block (verified R5)
// ---------------------------------------------------------------------------
__global__ __launch_bounds__(256) void kstab_mfma_kernel(
    const ushort* __restrict__ kb, const ushort* __restrict__ pb,
    unsigned* __restrict__ stab_enc)
{
    const int n0 = blockIdx.x * 256;
    const int bh = blockIdx.y;
    const int tid = threadIdx.x;
    const int lane = tid & 63, w = tid >> 6;
    const int q = lane >> 4, m16 = lane & 15;

    __shared__ ushort ks_s[256 * 72];
    __shared__ ushort pj_s[64 * 72];

#pragma unroll
    for (int t = 0; t < 8; ++t) {
        int idx = tid + t * 256;
        int r = idx >> 3, s = idx & 7;
        *(frag_t*)&ks_s[r * 72 + s * 8] =
            *(const frag_t*)(kb + ((size_t)bh * Nn + n0 + r) * 64 + s * 8);
    }
    __syncthreads();

    frag_t aq[4][2];
#pragma unroll
    for (int g = 0; g < 4; ++g)
#pragma unroll
        for (int s = 0; s < 2; ++s)
            aq[g][s] = *(const frag_t*)&ks_s[(w * 64 + g * 16 + m16) * 72 + s * 32 + q * 8];

    float mx = -3.0e38f;
#pragma unroll
    for (int mc = 0; mc < 5; ++mc) {
        __syncthreads();
#pragma unroll
        for (int t = 0; t < 2; ++t) {
            int idx = tid + t * 256;
            int r = idx >> 3, cc = idx & 7;   // hi half only
            *(frag_t*)&pj_s[r * 72 + cc * 8] =
                *(const frag_t*)(pb + ((size_t)mc * 64 + r) * 128 + cc * 8);
        }
        __syncthreads();
#pragma unroll
        for (int tm = 0; tm < 4; ++tm) {
            const int t = mc * 4 + tm;
            if (t > 16) continue;
            frag_t bh0 = *(const frag_t*)&pj_s[(tm * 16 + m16) * 72 + q * 8];
            frag_t bh1 = *(const frag_t*)&pj_s[(tm * 16 + m16) * 72 + 32 + q * 8];
            bool v = (t < 16) || (m16 < 10);
#pragma unroll
            for (int g = 0; g < 4; ++g) {
                f32x4 sa = (f32x4){0.f, 0.f, 0.f, 0.f};
                sa = __builtin_amdgcn_mfma_f32_16x16x32_bf16(aq[g][0], bh0, sa, 0, 0, 0);
                sa = __builtin_amdgcn_mfma_f32_16x16x32_bf16(aq[g][1], bh1, sa, 0, 0, 0);
                if (v) {
#pragma unroll
                    for (int r = 0; r < 4; ++r) mx = fmaxf(mx, sa[r]);
                }
            }
        }
    }
    mx = fmaxf(mx, __shfl_xor(mx, 1));
    mx = fmaxf(mx, __shfl_xor(mx, 2));
    mx = fmaxf(mx, __shfl_xor(mx, 4));
    mx = fmaxf(mx, __shfl_xor(mx, 8));
    mx = fmaxf(mx, __shfl_xor(mx, 16));
    mx = fmaxf(mx, __shfl_xor(mx, 32));
    if (lane == 0) atomicMax(stab_enc + bh, fenc(mx));
}

// ---------------------------------------------------------------------------
// ctx via MFMA (unchanged, verified)
// ---------------------------------------------------------------------------
__global__ __launch_bounds__(256) void ctx_mfma_kernel(
    const ushort* __restrict__ kb, const ushort* __restrict__ vT,
    const ushort* __restrict__ pb, const float* __restrict__ diagk,
    const unsigned* __restrict__ stab_enc,
    float* __restrict__ ctx, float* __restrict__ ksum)
{
    const int m0 = blockIdx.x * 64;
    const int nb = blockIdx.y;
    const int bh = blockIdx.z;
    const int tid = threadIdx.x;
    const int lane = tid & 63, w = tid >> 6;
    const int q = lane >> 4, m16 = lane & 15;
    const float kst = fdec(stab_enc[bh]);

    __shared__ ushort ks_s[32 * 72];
    __shared__ ushort pj_s[64 * 136];
    __shared__ ushort kf_s[64 * 40];
    __shared__ ushort vt_s[64 * 40];
    __shared__ float  diag_s[32];

    for (int u = tid; u < 1024; u += 256) {
        int r = u >> 4, c = (u & 15) * 8;
        *(frag_t*)&pj_s[r * 136 + c] = *(const frag_t*)(pb + (size_t)(m0 + r) * 128 + c);
    }

    f32x4 acc_c[4];
#pragma unroll
    for (int j = 0; j < 4; ++j) acc_c[j] = (f32x4){0.f, 0.f, 0.f, 0.f};
    float ksacc[2] = {0.f, 0.f};

    const int tn  = w & 1;
    const int tmb = (w >> 1) * 2;

    const int srow_k = tid >> 3, sseg_k = tid & 7;
    const int srow_v = tid >> 2, sseg_v = tid & 3;
    const size_t kbase = ((size_t)bh * Nn + nb * 1024 + srow_k) * 64 + sseg_k * 8;
    const size_t vbase = ((size_t)bh * 64 + srow_v) * Nn + nb * 1024 + sseg_v * 8;
    const float* dgp = diagk + (size_t)bh * Nn + nb * 1024;

    frag_t kreg = *(const frag_t*)(kb + kbase);
    frag_t vreg = *(const frag_t*)(vT + vbase);
    float4 dreg;
    if (tid < 8) dreg = *(const float4*)(dgp + tid * 4);

    for (int t = 0; t < 32; ++t) {
        __syncthreads();
        *(frag_t*)&ks_s[srow_k * 72 + sseg_k * 8] = kreg;
        *(frag_t*)&vt_s[srow_v * 40 + sseg_v * 8] = vreg;
        if (tid < 8) *(float4*)&diag_s[tid * 4] = dreg;
        __syncthreads();
        if (t < 31) {
            kreg = *(const frag_t*)(kb + kbase + (size_t)(t + 1) * 2048);
            vreg = *(const frag_t*)(vT + vbase + (size_t)(t + 1) * 32);
            if (tid < 8) dreg = *(const float4*)(dgp + (t + 1) * 32 + tid * 4);
        }

        f32x4 sa[2];
        sa[0] = (f32x4){0.f, 0.f, 0.f, 0.f};
        sa[1] = (f32x4){0.f, 0.f, 0.f, 0.f};
#pragma unroll
        for (int s = 0; s < 2; ++s) {
            frag_t a = *(const frag_t*)&ks_s[(tn * 16 + m16) * 72 + s * 32 + q * 8];
#pragma unroll
            for (int jj = 0; jj < 2; ++jj) {
                const ushort* prow = &pj_s[((tmb + jj) * 16 + m16) * 136 + s * 32 + q * 8];
                frag_t bhi = *(const frag_t*)prow;
                frag_t blo = *(const frag_t*)(prow + 64);
                sa[jj] = __builtin_amdgcn_mfma_f32_16x16x32_bf16(a, bhi, sa[jj], 0, 0, 0);
                sa[jj] = __builtin_amdgcn_mfma_f32_16x16x32_bf16(a, blo, sa[jj], 0, 0, 0);
            }
        }

#pragma unroll
        for (int jj = 0; jj < 2; ++jj) {
            int m_l = (tmb + jj) * 16 + m16;
            bool valid = (m0 + m_l) < Mm;
            sh4 pk;
            float vsum = 0.f;
#pragma unroll
            for (int r = 0; r < 4; ++r) {
                int n_l = tn * 16 + q * 4 + r;
                float val = valid ? RATIO * (__expf(sa[jj][r] - diag_s[n_l] - kst) + EPS_FAVOR) : 0.f;
                ushort hb = f2bf(val);
                pk[r] = (short)hb;
                vsum += bf2f(hb);
            }
            ksacc[jj] += vsum;
            *(sh4*)&kf_s[m_l * 40 + tn * 16 + q * 4] = pk;
        }
        __syncthreads();

        {
            frag_t a = *(const frag_t*)&kf_s[(w * 16 + m16) * 40 + q * 8];
#pragma unroll
            for (int j = 0; j < 4; ++j) {
                frag_t b = *(const frag_t*)&vt_s[(j * 16 + m16) * 40 + q * 8];
                acc_c[j] = __builtin_amdgcn_mfma_f32_16x16x32_bf16(a, b, acc_c[j], 0, 0, 0);
            }
        }
    }

#pragma unroll
    for (int j = 0; j < 4; ++j)
#pragma unroll
        for (int r = 0; r < 4; ++r) {
            int m = m0 + w * 16 + q * 4 + r;
            if (m < Mm)
                atomicAdd(&ctx[((size_t)bh * Mm + m) * 64 + j * 16 + m16], acc_c[j][r]);
        }
#pragma unroll
    for (int jj = 0; jj < 2; ++jj) {
        float v = ksacc[jj];
        v += __shfl_xor(v, 16);
        v += __shfl_xor(v, 32);
        int m = m0 + (tmb + jj) * 16 + m16;
        if (q == 0 && m < Mm) atomicAdd(&ksum[(size_t)bh * Mm + m], v);
    }
}

// ---------------------------------------------------------------------------
// q-side via MFMA v3 (verified R7): unified 10-chunk T14 pipeline
// ---------------------------------------------------------------------------
__global__ __launch_bounds__(256, 3) void qout_mfma_kernel(
    const ushort* __restrict__ qb, const ushort* __restrict__ pb,
    const ushort* __restrict__ cT, const float* __restrict__ ksum,
    ushort* __restrict__ attnb)
{
    const int n0 = blockIdx.x * 64;
    const int bh = blockIdx.y;
    const int b = bh >> 4, h = bh & 15;
    const int tid = threadIdx.x;
    const int lane = tid & 63, w = tid >> 6;
    const int q = lane >> 4, m16 = lane & 15;

    __shared__ ushort qs_s[64 * 64];        //  8.0 KB (linear, gld16-staged)
    __shared__ ushort pj_s[2 * 64 * 136];   // 34.0 KB ring
    __shared__ ushort qf_s[64 * 72];        //  9.0 KB chunk buffer
    __shared__ float  diag_s[64];
    __shared__ float  ksum_s[320];

    const ushort* cbase = cT + (size_t)bh * 40960;

#define LOADCH(i_) {                                                              \
        for (int t_ = 0; t_ < 4; ++t_) {                                          \
            int idx_ = tid + t_ * 256, rr_ = idx_ >> 4, cc_ = idx_ & 15;          \
            g[t_] = ((i_) <= 4)                                                   \
                ? *(const frag_t*)(pb + (size_t)((i_) * 64 + rr_) * 128 + cc_ * 8)\
                : *(const frag_t*)(cbase + (size_t)rr_ * 640 + (cc_ >> 3) * 320   \
                                   + ((i_) - 5) * 64 + (cc_ & 7) * 8);            \
        } }
#define STORECH(i_) {                                                             \
        ushort* sl_ = pj_s + (((i_) & 1) * 8704);                                 \
        for (int t_ = 0; t_ < 4; ++t_) {                                          \
            int idx_ = tid + t_ * 256, rr_ = idx_ >> 4, cc_ = idx_ & 15;          \
            *(frag_t*)&sl_[rr_ * 136 + cc_ * 8] = g[t_];                          \
        } }

    for (int m = tid; m < 320; m += 256)
        ksum_s[m] = (m < Mm) ? ksum[(size_t)bh * Mm + m] : 0.f;

    const ushort* qsrc = qb + ((size_t)bh * Nn + n0) * 64;
    gld16(qsrc + tid * 8,        (void*)(qs_s + tid * 8));
    gld16(qsrc + 2048 + tid * 8, (void*)(qs_s + 2048 + tid * 8));

    frag_t g[4];
    LOADCH(0);
    STORECH(0);
    LOADCH(1);
    asm volatile("s_waitcnt vmcnt(4)" ::: "memory");
    __builtin_amdgcn_sched_barrier(0);
    SYNC_LDS();

    if (tid < 64) {
        float s = 0.f;
#pragma unroll 8
        for (int k = 0; k < 64; ++k) { float f = bf2f(qs_s[tid * 64 + k]); s += f * f; }
        diag_s[tid] = 0.5f * s;
    }
    frag_t aq[2];
#pragma unroll
    for (int s = 0; s < 2; ++s)
        aq[s] = *(const frag_t*)&qs_s[(w * 16 + m16) * 64 + s * 32 + q * 8];
    SYNC_LDS();

    f32x4 sA[20];
#pragma unroll
    for (int t = 0; t < 20; ++t) sA[t] = (f32x4){0.f, 0.f, 0.f, 0.f};

#pragma unroll
    for (int mc = 0; mc < 5; ++mc) {
        const ushort* sl = pj_s + ((mc & 1) * 8704);
        __builtin_amdgcn_s_setprio(1);
#pragma unroll
        for (int tm = 0; tm < 4; ++tm)
#pragma unroll
            for (int s = 0; s < 2; ++s) {
                const ushort* pr = &sl[(tm * 16 + m16) * 136 + s * 32 + q * 8];
                frag_t bhi = *(const frag_t*)pr;
                frag_t blo = *(const frag_t*)(pr + 64);
                sA[mc * 4 + tm] = __builtin_amdgcn_mfma_f32_16x16x32_bf16(aq[s], bhi, sA[mc * 4 + tm], 0, 0, 0);
                sA[mc * 4 + tm] = __builtin_amdgcn_mfma_f32_16x16x32_bf16(aq[s], blo, sA[mc * 4 + tm], 0, 0, 0);
            }
        __builtin_amdgcn_s_setprio(0);
        STORECH(mc + 1);
        LOADCH(mc + 2);
        SYNC_LDS();
    }

    float mx[4] = {-3.0e38f, -3.0e38f, -3.0e38f, -3.0e38f};
#pragma unroll
    for (int t = 0; t < 17; ++t) {
        bool v = (t < 16) || (m16 < 10);
        if (v) {
#pragma unroll
            for (int r = 0; r < 4; ++r) mx[r] = fmaxf(mx[r], sA[t][r]);
        }
    }
#pragma unroll
    for (int r = 0; r < 4; ++r) {
        float v = mx[r];
        v = fmaxf(v, __shfl_xor(v, 1));
        v = fmaxf(v, __shfl_xor(v, 2));
        v = fmaxf(v, __shfl_xor(v, 4));
        v = fmaxf(v, __shfl_xor(v, 8));
        mx[r] = v;
    }
    float dg[4];
#pragma unroll
    for (int r = 0; r < 4; ++r) dg[r] = diag_s[w * 16 + q * 4 + r];

    float ds[4] = {0.f, 0.f, 0.f, 0.f};
    f32x4 oA[4];
#pragma unroll
    for (int dt = 0; dt < 4; ++dt) oA[dt] = (f32x4){0.f, 0.f, 0.f, 0.f};

#pragma unroll
    for (int mc = 0; mc < 5; ++mc) {
#pragma unroll
        for (int tm = 0; tm < 4; ++tm) {
            int t = mc * 4 + tm;
            float ksm = ksum_s[t * 16 + m16];
#pragma unroll
            for (int r = 0; r < 4; ++r) {
                ushort hb = f2bf(RATIO * (__expf(sA[t][r] - dg[r] - mx[r]) + EPS_FAVOR));
                ds[r] += bf2f(hb) * ksm;
                qf_s[(w * 16 + q * 4 + r) * 72 + tm * 16 + m16] = hb;
            }
        }
        const ushort* sl = pj_s + (((mc + 5) & 1) * 8704);
        __builtin_amdgcn_s_setprio(1);
#pragma unroll
        for (int s = 0; s < 2; ++s) {
            frag_t a = *(const frag_t*)&qf_s[(w * 16 + m16) * 72 + s * 32 + q * 8];
#pragma unroll
            for (int dt = 0; dt < 4; ++dt) {
                const ushort* pr = &sl[(dt * 16 + m16) * 136 + s * 32 + q * 8];
                frag_t bhi = *(const frag_t*)pr;
                frag_t blo = *(const frag_t*)(pr + 64);
                oA[dt] = __builtin_amdgcn_mfma_f32_16x16x32_bf16(a, bhi, oA[dt], 0, 0, 0);
                oA[dt] = __builtin_amdgcn_mfma_f32_16x16x32_bf16(a, blo, oA[dt], 0, 0, 0);
            }
        }
        __builtin_amdgcn_s_setprio(0);
        if (mc + 6 <= 9) STORECH(mc + 6);
        if (mc + 7 <= 9) LOADCH(mc + 7);
        SYNC_LDS();
    }
#undef LOADCH
#undef STORECH

#pragma unroll
    for (int r = 0; r < 4; ++r) {
        float v = ds[r];
        v += __shfl_xor(v, 1);
        v += __shfl_xor(v, 2);
        v += __shfl_xor(v, 4);
        v += __shfl_xor(v, 8);
        ds[r] = 1.0f / v;
    }
#pragma unroll
    for (int dt = 0; dt < 4; ++dt)
#pragma unroll
        for (int r = 0; r < 4; ++r) {
            int n = n0 + w * 16 + q * 4 + r;
            attnb[((size_t)(b * Nn + n)) * Dd + h * 64 + dt * 16 + m16] =
                f2bf(oA[dt][r] * ds[r]);
        }
}

// ---------------------------------------------------------------------------
// LayerNorm: one block per row of 1024
// ---------------------------------------------------------------------------
__global__ __launch_bounds__(256) void ln_kernel(
    const float* __restrict__ y, const float* __restrict__ gamma,
    const float* __restrict__ beta, float* __restrict__ out)
{
    const int row = blockIdx.x;
    const int tid = threadIdx.x;
    float4 v = *(const float4*)(y + (size_t)row * Dd + tid * 4);
    float s = v.x + v.y + v.z + v.w;
    float q = v.x * v.x + v.y * v.y + v.z * v.z + v.w * v.w;
    __shared__ float rs[256], rq[256];
    rs[tid] = s; rq[tid] = q;
    __syncthreads();
    for (int off = 128; off > 0; off >>= 1) {
        if (tid < off) { rs[tid] += rs[tid + off]; rq[tid] += rq[tid + off]; }
        __syncthreads();
    }
    float mu = rs[0] * (1.0f / Dd);
    float var = rq[0] * (1.0f / Dd) - mu * mu;
    float rstd = rsqrtf(var + EPS_LN);
    float4 gm = *(const float4*)(gamma + tid * 4);
    float4 bt = *(const float4*)(beta + tid * 4);
    float4 o;
    o.x = (v.x - mu) * rstd * gm.x + bt.x;
    o.y = (v.y - mu) * rstd * gm.y + bt.y;
    o.z = (v.z - mu) * rstd * gm.z + bt.z;
    o.w = (v.w - mu) * rstd * gm.w + bt.w;
    *(float4*)(out + (size_t)row * Dd + tid * 4) = o;
}

// ---------------------------------------------------------------------------
extern "C" void kernel_launch(void* const* d_in, const int* in_sizes, int n_in,
                              void* d_out, int out_size, void* d_ws, size_t ws_size,
                              hipStream_t stream) {
    const float* x     = (const float*)d_in[0];
    const float* Wq    = (const float*)d_in[1];
    const float* Wk    = (const float*)d_in[2];
    const float* Wv    = (const float*)d_in[3];
    const float* Wo    = (const float*)d_in[4];
    const float* bo    = (const float*)d_in[5];
    const float* proj  = (const float*)d_in[6];
    const float* gamma = (const float*)d_in[7];
    const float* beta  = (const float*)d_in[8];
    float* out = (float*)d_out;

    const size_t TS = 16777216;           // tokens(16384) * 1024
    ushort* xb  = (ushort*)d_ws;          // x bf16; reused as attnb after QKV gemm
    ushort* qb  = xb + TS;
    ushort* kb  = qb + TS;
    ushort* vb  = kb + TS;                // holds vT [bh][64][4096] (gemm z==2 writes)
    ushort* WTq = vb + TS;
    ushort* WTk = WTq + 1048576;
    ushort* WTv = WTk + 1048576;
    ushort* WTo = WTv + 1048576;
    float*  ctx  = (float*)(WTo + 1048576);         // BH*M*64 fp32
    float*  ksum = ctx + (size_t)BHh * Mm * DHh;    // BH*M
    unsigned* stab = (unsigned*)(ksum + (size_t)BHh * Mm);
    ushort* attnb = xb;                   // token-major bf16 attn (after gemm consumed xb)
    float*  yres  = (float*)qb;           // fp32, overlays qb+kb after qout
    ushort* vT     = vb;                  // [bh][64][4096] bf16, direct from gemm z==2
    float*  diagk  = (float*)WTq;         // 1 MB in the 2 MB WTq slot (after gemm)
    ushort* projb2 = WTk;                 // 80 KB in the 2 MB WTk slot (after gemm)
    ushort* ctxT   = vb;                  // [bh][64][640] bf16 hi|lo (after ctx consumed vT)

    hipMemsetAsync(ctx, 0, (size_t)BHh * Mm * DHh * sizeof(float), stream);
    hipMemsetAsync(ksum, 0, (size_t)BHh * Mm * sizeof(float), stream);
    hipMemsetAsync(stab, 0, BHh * sizeof(unsigned), stream);

    conv_x_kernel<<<8192, 256, 0, stream>>>(x, xb);
    conv_wt_kernel<<<dim3(16, 16, 4), 256, 0, stream>>>(Wq, Wk, Wv, Wo, WTq, WTk, WTv, WTo);

    gemm256<<<dim3(64, 4, 3), 512, 0, stream>>>(xb, WTq, WTk, WTv, qb, kb, vT,
                                                nullptr, nullptr, nullptr, 0);

    diag_kernel<<<1024, 256, 0, stream>>>(kb, diagk);
    conv_proj_kernel<<<80, 256, 0, stream>>>(proj, projb2);

    kstab_mfma_kernel<<<dim3(Nn / 256, BHh), 256, 0, stream>>>(kb, projb2, stab);

    ctx_mfma_kernel<<<dim3(5, 4, BHh), 256, 0, stream>>>(kb, vT, projb2, diagk, stab,
                                                         ctx, ksum);

    ctx2bt_kernel<<<dim3(5, BHh), 256, 0, stream>>>(ctx, ctxT);

    qout_mfma_kernel<<<dim3(Nn / 64, BHh), 256, 0, stream>>>(qb, projb2, ctxT, ksum, attnb);

    gemm256<<<dim3(64, 4, 1), 512, 0, stream>>>(attnb, WTo, nullptr, nullptr,
                                                nullptr, nullptr, nullptr, bo, x, yres, 1);
    ln_kernel<<<16384, 256, 0, stream>>>(yres, gamma, beta, out);
}

// Round 9
// 561.560 us; speedup vs baseline: 1.2947x; 1.0019x over previous
//
#include <hip/hip_runtime.h>
#include <hip/hip_bf16.h>
#include <math.h>

// Problem constants
#define Bb 4
#define Nn 4096
#define Hh 16
#define DHh 64
#define Mm 266
#define Dd 1024
#define BHh (Bb*Hh)

#define DN_SCALE 0.35355339059327373f   // 64^-0.25
#define RATIO 0.06131393394849658f      // 266^-0.5
#define EPS_FAVOR 1e-4f
#define EPS_LN 1e-5f

typedef __attribute__((ext_vector_type(8))) short frag_t;   // 8 x bf16
typedef __attribute__((ext_vector_type(4))) short sh4;      // 4 x bf16
typedef __attribute__((ext_vector_type(4))) float f32x4;

__device__ __forceinline__ ushort f2bf(float f) {
    unsigned u = __float_as_uint(f);
    return (ushort)((u + 0x7FFFu + ((u >> 16) & 1u)) >> 16);
}
__device__ __forceinline__ float bf2f(ushort h) {
    return __uint_as_float(((unsigned)h) << 16);
}
__device__ __forceinline__ unsigned fenc(float f) {
    unsigned u = __float_as_uint(f);
    return (u & 0x80000000u) ? ~u : (u | 0x80000000u);
}
__device__ __forceinline__ float fdec(unsigned e) {
    unsigned u = (e & 0x80000000u) ? (e ^ 0x80000000u) : ~e;
    return __uint_as_float(u);
}
__device__ __forceinline__ void gld16(const void* g, void* l) {
    __builtin_amdgcn_global_load_lds((const __attribute__((address_space(1))) unsigned int*)g,
                                     (__attribute__((address_space(3))) unsigned int*)l, 16, 0, 0);
}

// raw barrier with LDS drain only (global prefetches stay in flight)
#define SYNC_LDS() do {                                             \
        asm volatile("s_waitcnt lgkmcnt(0)" ::: "memory");          \
        __builtin_amdgcn_sched_barrier(0);                          \
        __builtin_amdgcn_s_barrier();                               \
        __builtin_amdgcn_sched_barrier(0);                          \
    } while (0)

// ---------------------------------------------------------------------------
// prep: x fp32 -> bf16
// ---------------------------------------------------------------------------
__global__ __launch_bounds__(256) void conv_x_kernel(const float* __restrict__ x,
                                                     ushort* __restrict__ xb) {
    size_t i = ((size_t)blockIdx.x * 256 + threadIdx.x) * 8;
    float4 f0 = *(const float4*)(x + i);
    float4 f1 = *(const float4*)(x + i + 4);
    uint4 o;
    o.x = (unsigned)f2bf(f0.x) | ((unsigned)f2bf(f0.y) << 16);
    o.y = (unsigned)f2bf(f0.z) | ((unsigned)f2bf(f0.w) << 16);
    o.z = (unsigned)f2bf(f1.x) | ((unsigned)f2bf(f1.y) << 16);
    o.w = (unsigned)f2bf(f1.z) | ((unsigned)f2bf(f1.w) << 16);
    *(uint4*)(xb + i) = o;
}

// prep: W[k][n] fp32 -> WT[n][k] bf16 (K-contiguous for the B^T GEMM)
__global__ __launch_bounds__(256) void conv_wt_kernel(
    const float* __restrict__ Wq, const float* __restrict__ Wk,
    const float* __restrict__ Wv, const float* __restrict__ Wo,
    ushort* __restrict__ Tq, ushort* __restrict__ Tk,
    ushort* __restrict__ Tv, ushort* __restrict__ To) {
    const int z = blockIdx.z;
    const float* W = z == 0 ? Wq : z == 1 ? Wk : z == 2 ? Wv : Wo;
    ushort* WT = z == 0 ? Tq : z == 1 ? Tk : z == 2 ? Tv : To;
    __shared__ float tls[64][65];
    const int tid = threadIdx.x;
    const int n0 = blockIdx.x * 64, k0 = blockIdx.y * 64;
    const int r = tid >> 2, seg = tid & 3;
#pragma unroll
    for (int i = 0; i < 4; ++i) {
        float4 f = *(const float4*)(W + (size_t)(k0 + r) * 1024 + n0 + seg * 16 + i * 4);
        tls[r][seg * 16 + i * 4 + 0] = f.x;
        tls[r][seg * 16 + i * 4 + 1] = f.y;
        tls[r][seg * 16 + i * 4 + 2] = f.z;
        tls[r][seg * 16 + i * 4 + 3] = f.w;
    }
    __syncthreads();
    const int nl = tid >> 2;
#pragma unroll
    for (int i = 0; i < 16; ++i)
        WT[(size_t)(n0 + nl) * 1024 + k0 + seg * 16 + i] = f2bf(tls[seg * 16 + i][nl]);
}

// prep: proj fp32 [266][64] -> bf16 hi/lo [320][128], zero-padded rows
__global__ __launch_bounds__(256) void conv_proj_kernel(const float* __restrict__ proj,
                                                        ushort* __restrict__ pb) {
    const int idx = blockIdx.x * 256 + threadIdx.x;   // 320*64 = 20480
    const int m = idx >> 6, k = idx & 63;
    float v = (m < Mm) ? proj[m * 64 + k] : 0.f;
    ushort hi = f2bf(v);
    float lo = v - bf2f(hi);
    pb[m * 128 + k] = hi;
    pb[m * 128 + 64 + k] = f2bf(lo);
}

// prep: diag[bh*4096+n] = 0.5 * sum_k kb[n][k]^2
__global__ __launch_bounds__(256) void diag_kernel(const ushort* __restrict__ kb,
                                                   float* __restrict__ dg) {
    const size_t i = (size_t)blockIdx.x * 256 + threadIdx.x;
    const ushort* p = kb + i * 64;
    float s = 0.f;
#pragma unroll
    for (int seg = 0; seg < 8; ++seg) {
        frag_t a = *(const frag_t*)(p + seg * 8);
#pragma unroll
        for (int j = 0; j < 8; ++j) { float f = bf2f((ushort)a[j]); s += f * f; }
    }
    dg[i] = 0.5f * s;
}

// prep: ctx fp32 [bh][m][64] -> ctxT hi/lo bf16 [bh][64 d][320 hi | 320 lo]
__global__ __launch_bounds__(256) void ctx2bt_kernel(const float* __restrict__ ctx,
                                                     ushort* __restrict__ cT) {
    const int mc = blockIdx.x;       // 0..4
    const int bh = blockIdx.y;
    const int tid = threadIdx.x;
    __shared__ float tls[64][65];
    const int r = tid >> 2, cs = tid & 3;
    const int gm = mc * 64 + r;
#pragma unroll
    for (int i = 0; i < 4; ++i) {
        float4 f = {0.f, 0.f, 0.f, 0.f};
        if (gm < Mm) f = *(const float4*)(ctx + ((size_t)bh * Mm + gm) * 64 + cs * 16 + i * 4);
        tls[r][cs * 16 + i * 4 + 0] = f.x;
        tls[r][cs * 16 + i * 4 + 1] = f.y;
        tls[r][cs * 16 + i * 4 + 2] = f.z;
        tls[r][cs * 16 + i * 4 + 3] = f.w;
    }
    __syncthreads();
    const int d = tid >> 2, ms = tid & 3;
    unsigned hi[8], lo[8];
#pragma unroll
    for (int j = 0; j < 8; ++j) {
        float v0 = tls[ms * 16 + j * 2][d];
        float v1 = tls[ms * 16 + j * 2 + 1][d];
        ushort h0 = f2bf(v0), h1 = f2bf(v1);
        ushort l0 = f2bf(v0 - bf2f(h0)), l1 = f2bf(v1 - bf2f(h1));
        hi[j] = (unsigned)h0 | ((unsigned)h1 << 16);
        lo[j] = (unsigned)l0 | ((unsigned)l1 << 16);
    }
    size_t base = (size_t)bh * 40960 + (size_t)d * 640 + mc * 64 + ms * 16;
    uint4 a = {hi[0], hi[1], hi[2], hi[3]};
    uint4 b = {hi[4], hi[5], hi[6], hi[7]};
    uint4 c = {lo[0], lo[1], lo[2], lo[3]};
    uint4 e = {lo[4], lo[5], lo[6], lo[7]};
    *(uint4*)(cT + base) = a;
    *(uint4*)(cT + base + 8) = b;
    *(uint4*)(cT + base + 320) = c;
    *(uint4*)(cT + base + 328) = e;
}

// ---------------------------------------------------------------------------
// 256x256 deep-ring bf16 GEMM, 128 KiB static LDS (8 half-slots = 4 K-tiles,
// BK=32), 8 waves (2Mx4N). REGISTER double-buffer: during tile kt's 32-MFMA
// cluster, the wave ds_reads tile kt+1's fragments (resident: vmcnt(4) at
// the top guarantees tiles <= kt+1 staged, barrier makes it block-wide).
// MFMAs never wait on LDS. STG(kt+3) overwrites tile kt-1's slots, whose
// reads retired two barriers ago. ONE barrier per K-tile. XOR-swizzled LDS.
// mode 0: head-major bf16 out (z 0,1 scaled; z==2 writes transposed vT)
// mode 1: fp32 + bias + residual
// ---------------------------------------------------------------------------
__global__ __launch_bounds__(512, 2) void gemm256(
    const ushort* __restrict__ A,
    const ushort* __restrict__ W0, const ushort* __restrict__ W1, const ushort* __restrict__ W2,
    ushort* __restrict__ o0, ushort* __restrict__ o1, ushort* __restrict__ o2,
    const float* __restrict__ bo, const float* __restrict__ xres, float* __restrict__ yres,
    int mode)
{
    __shared__ ushort smem[65536];   // 8 half-slots x (A 4096 | B 4096) ushorts = 128 KiB
    const int tid = threadIdx.x;
    const int lane = tid & 63, w = tid >> 6;
    const int q = lane >> 4, m16 = lane & 15;
    const int wm = w >> 2, wn = w & 3;
    const int row0 = blockIdx.x * 256, col0 = blockIdx.y * 256;
    const int z = blockIdx.z;
    const ushort* WT = (mode == 0) ? (z == 0 ? W0 : z == 1 ? W1 : W2) : W0;

    const int srow = tid >> 2, sseg = tid & 3;
    const int ksw = (sseg ^ ((srow >> 1) & 3)) * 8;   // pre-swizzled SOURCE k-chunk
    const int dst = tid * 8;                          // linear LDS dest
    const int sq  = (q ^ ((m16 >> 1) & 3)) * 8;      // swizzled READ k-chunk

#define STG(T_) do {                                                          \
        int s0_ = (2 * (T_)) & 7, s1_ = (2 * (T_) + 1) & 7;                   \
        gld16(A  + (size_t)(row0 + srow) * 1024 + (T_) * 32 + ksw,            \
              smem + s0_ * 8192 + dst);                                       \
        gld16(WT + (size_t)(col0 + srow) * 1024 + (T_) * 32 + ksw,            \
              smem + s0_ * 8192 + 4096 + dst);                                \
        gld16(A  + (size_t)(row0 + 128 + srow) * 1024 + (T_) * 32 + ksw,      \
              smem + s1_ * 8192 + dst);                                       \
        gld16(WT + (size_t)(col0 + 128 + srow) * 1024 + (T_) * 32 + ksw,      \
              smem + s1_ * 8192 + 4096 + dst);                                \
    } while (0)

    f32x4 acc[8][4];
#pragma unroll
    for (int i = 0; i < 8; ++i)
#pragma unroll
        for (int j = 0; j < 4; ++j) acc[i][j] = (f32x4){0.f, 0.f, 0.f, 0.f};

    frag_t afA[8], bfA[4], afB[8], bfB[4];

    STG(0);
    STG(1);
    STG(2);

    // prologue: tile 0 staged -> read its fragments into set A
    asm volatile("s_waitcnt vmcnt(8)" ::: "memory");
    __builtin_amdgcn_sched_barrier(0);
    __builtin_amdgcn_s_barrier();
    __builtin_amdgcn_sched_barrier(0);
    {
        const ushort* A0 = smem + ((wm & 7) * 8192);
        const ushort* B0 = smem + (((wn >> 1) & 7) * 8192) + 4096;
#pragma unroll
        for (int i = 0; i < 8; ++i)
            afA[i] = *(const frag_t*)&A0[(i * 16 + m16) * 32 + sq];
#pragma unroll
        for (int j = 0; j < 4; ++j)
            bfA[j] = *(const frag_t*)&B0[((wn & 1) * 64 + j * 16 + m16) * 32 + sq];
    }

    // One step: MFMA tile KT_ from CURA/CURB while reading tile KT_+1 -> NXTA/NXTB
#define STEP(CURA, CURB, NXTA, NXTB, KT_) do {                                    \
        if ((KT_) < 30) { asm volatile("s_waitcnt vmcnt(4)" ::: "memory"); }      \
        else            { asm volatile("s_waitcnt vmcnt(0)" ::: "memory"); }      \
        __builtin_amdgcn_sched_barrier(0);                                        \
        __builtin_amdgcn_s_barrier();                                             \
        __builtin_amdgcn_sched_barrier(0);                                        \
        if ((KT_) + 3 < 32) STG((KT_) + 3);                                       \
        const ushort* An_ = smem + (((2 * ((KT_) + 1) + wm) & 7) * 8192);         \
        const ushort* Bn_ = smem + (((2 * ((KT_) + 1) + (wn >> 1)) & 7) * 8192) + 4096; \
        __builtin_amdgcn_s_setprio(1);                                            \
        _Pragma("unroll")                                                         \
        for (int g = 0; g < 4; ++g) {                                             \
            if ((KT_) + 1 < 32) {                                                 \
                NXTA[2 * g]     = *(const frag_t*)&An_[((2 * g) * 16 + m16) * 32 + sq];     \
                NXTA[2 * g + 1] = *(const frag_t*)&An_[((2 * g + 1) * 16 + m16) * 32 + sq]; \
                NXTB[g]         = *(const frag_t*)&Bn_[((wn & 1) * 64 + g * 16 + m16) * 32 + sq]; \
            }                                                                     \
            _Pragma("unroll")                                                     \
            for (int j = 0; j < 4; ++j) {                                         \
                acc[2 * g][j]     = __builtin_amdgcn_mfma_f32_16x16x32_bf16(CURA[2 * g],     CURB[j], acc[2 * g][j], 0, 0, 0);     \
                acc[2 * g + 1][j] = __builtin_amdgcn_mfma_f32_16x16x32_bf16(CURA[2 * g + 1], CURB[j], acc[2 * g + 1][j], 0, 0, 0); \
            }                                                                     \
        }                                                                         \
        __builtin_amdgcn_s_setprio(0);                                            \
    } while (0)

    for (int kt = 0; kt < 32; kt += 2) {
        STEP(afA, bfA, afB, bfB, kt);
        STEP(afB, bfB, afA, bfA, kt + 1);
    }
#undef STEP
#undef STG

    const int b = row0 >> 12;
    if (mode == 0) {
        if (z == 2) {
#pragma unroll
            for (int i = 0; i < 8; ++i)
#pragma unroll
                for (int j = 0; j < 4; ++j) {
                    int col = col0 + wn * 64 + j * 16 + m16;
                    size_t rowbase = ((size_t)((b << 4) + (col >> 6)) * 64 + (col & 63)) * 4096;
                    int n = (row0 & 4095) + wm * 128 + i * 16 + q * 4;
                    sh4 pk;
#pragma unroll
                    for (int r = 0; r < 4; ++r) pk[r] = (short)f2bf(acc[i][j][r]);
                    *(sh4*)(o2 + rowbase + n) = pk;
                }
        } else {
            ushort* outp = (z == 0) ? o0 : o1;
#pragma unroll
            for (int c = 0; c < 4; ++c) {
                __builtin_amdgcn_s_barrier();
                if (wm == (c >> 1)) {
#pragma unroll
                    for (int i2 = 0; i2 < 4; ++i2) {
                        int i = (c & 1) * 4 + i2;
#pragma unroll
                        for (int j = 0; j < 4; ++j)
#pragma unroll
                            for (int r = 0; r < 4; ++r)
                                smem[(i2 * 16 + q * 4 + r) * 264 + wn * 64 + j * 16 + m16] =
                                    f2bf(acc[i][j][r] * DN_SCALE);
                    }
                }
                __builtin_amdgcn_s_barrier();
#pragma unroll
                for (int it = 0; it < 4; ++it) {
                    int idx = it * 512 + tid;
                    int lr = idx >> 5, ch = idx & 31;
                    frag_t v = *(const frag_t*)&smem[lr * 264 + ch * 8];
                    int n = (row0 & 4095) + c * 64 + lr;
                    int h = (col0 >> 6) + (ch >> 3);
                    int dh = (ch & 7) * 8;
                    *(frag_t*)(outp + ((size_t)((b << 4) + h) * 4096 + n) * 64 + dh) = v;
                }
            }
        }
    } else {
#pragma unroll
        for (int i = 0; i < 8; ++i)
#pragma unroll
            for (int j = 0; j < 4; ++j)
#pragma unroll
                for (int r = 0; r < 4; ++r) {
                    int row = row0 + wm * 128 + i * 16 + q * 4 + r;
                    int col = col0 + wn * 64 + j * 16 + m16;
                    size_t off = (size_t)row * 1024 + col;
                    yres[off] = acc[i][j][r] + bo[col] + xres[off];
                }
    }
}

// ---------------------------------------------------------------------------
// k-stab via MFMA, 256 rows/block (verified R5)
// ---------------------------------------------------------------------------
__global__ __launch_bounds__(256) void kstab_mfma_kernel(
    const ushort* __restrict__ kb, const ushort* __restrict__ pb,
    unsigned* __restrict__ stab_enc)
{
    const int n0 = blockIdx.x * 256;
    const int bh = blockIdx.y;
    const int tid = threadIdx.x;
    const int lane = tid & 63, w = tid >> 6;
    const int q = lane >> 4, m16 = lane & 15;

    __shared__ ushort ks_s[256 * 72];
    __shared__ ushort pj_s[64 * 72];

#pragma unroll
    for (int t = 0; t < 8; ++t) {
        int idx = tid + t * 256;
        int r = idx >> 3, s = idx & 7;
        *(frag_t*)&ks_s[r * 72 + s * 8] =
            *(const frag_t*)(kb + ((size_t)bh * Nn + n0 + r) * 64 + s * 8);
    }
    __syncthreads();

    frag_t aq[4][2];
#pragma unroll
    for (int g = 0; g < 4; ++g)
#pragma unroll
        for (int s = 0; s < 2; ++s)
            aq[g][s] = *(const frag_t*)&ks_s[(w * 64 + g * 16 + m16) * 72 + s * 32 + q * 8];

    float mx = -3.0e38f;
#pragma unroll
    for (int mc = 0; mc < 5; ++mc) {
        __syncthreads();
#pragma unroll
        for (int t = 0; t < 2; ++t) {
            int idx = tid + t * 256;
            int r = idx >> 3, cc = idx & 7;   // hi half only
            *(frag_t*)&pj_s[r * 72 + cc * 8] =
                *(const frag_t*)(pb + ((size_t)mc * 64 + r) * 128 + cc * 8);
        }
        __syncthreads();
#pragma unroll
        for (int tm = 0; tm < 4; ++tm) {
            const int t = mc * 4 + tm;
            if (t > 16) continue;
            frag_t bh0 = *(const frag_t*)&pj_s[(tm * 16 + m16) * 72 + q * 8];
            frag_t bh1 = *(const frag_t*)&pj_s[(tm * 16 + m16) * 72 + 32 + q * 8];
            bool v = (t < 16) || (m16 < 10);
#pragma unroll
            for (int g = 0; g < 4; ++g) {
                f32x4 sa = (f32x4){0.f, 0.f, 0.f, 0.f};
                sa = __builtin_amdgcn_mfma_f32_16x16x32_bf16(aq[g][0], bh0, sa, 0, 0, 0);
                sa = __builtin_amdgcn_mfma_f32_16x16x32_bf16(aq[g][1], bh1, sa, 0, 0, 0);
                if (v) {
#pragma unroll
                    for (int r = 0; r < 4; ++r) mx = fmaxf(mx, sa[r]);
                }
            }
        }
    }
    mx = fmaxf(mx, __shfl_xor(mx, 1));
    mx = fmaxf(mx, __shfl_xor(mx, 2));
    mx = fmaxf(mx, __shfl_xor(mx, 4));
    mx = fmaxf(mx, __shfl_xor(mx, 8));
    mx = fmaxf(mx, __shfl_xor(mx, 16));
    mx = fmaxf(mx, __shfl_xor(mx, 32));
    if (lane == 0) atomicMax(stab_enc + bh, fenc(mx));
}

// ---------------------------------------------------------------------------
// ctx via MFMA (unchanged, verified)
// ---------------------------------------------------------------------------
__global__ __launch_bounds__(256) void ctx_mfma_kernel(
    const ushort* __restrict__ kb, const ushort* __restrict__ vT,
    const ushort* __restrict__ pb, const float* __restrict__ diagk,
    const unsigned* __restrict__ stab_enc,
    float* __restrict__ ctx, float* __restrict__ ksum)
{
    const int m0 = blockIdx.x * 64;
    const int nb = blockIdx.y;
    const int bh = blockIdx.z;
    const int tid = threadIdx.x;
    const int lane = tid & 63, w = tid >> 6;
    const int q = lane >> 4, m16 = lane & 15;
    const float kst = fdec(stab_enc[bh]);

    __shared__ ushort ks_s[32 * 72];
    __shared__ ushort pj_s[64 * 136];
    __shared__ ushort kf_s[64 * 40];
    __shared__ ushort vt_s[64 * 40];
    __shared__ float  diag_s[32];

    for (int u = tid; u < 1024; u += 256) {
        int r = u >> 4, c = (u & 15) * 8;
        *(frag_t*)&pj_s[r * 136 + c] = *(const frag_t*)(pb + (size_t)(m0 + r) * 128 + c);
    }

    f32x4 acc_c[4];
#pragma unroll
    for (int j = 0; j < 4; ++j) acc_c[j] = (f32x4){0.f, 0.f, 0.f, 0.f};
    float ksacc[2] = {0.f, 0.f};

    const int tn  = w & 1;
    const int tmb = (w >> 1) * 2;

    const int srow_k = tid >> 3, sseg_k = tid & 7;
    const int srow_v = tid >> 2, sseg_v = tid & 3;
    const size_t kbase = ((size_t)bh * Nn + nb * 1024 + srow_k) * 64 + sseg_k * 8;
    const size_t vbase = ((size_t)bh * 64 + srow_v) * Nn + nb * 1024 + sseg_v * 8;
    const float* dgp = diagk + (size_t)bh * Nn + nb * 1024;

    frag_t kreg = *(const frag_t*)(kb + kbase);
    frag_t vreg = *(const frag_t*)(vT + vbase);
    float4 dreg;
    if (tid < 8) dreg = *(const float4*)(dgp + tid * 4);

    for (int t = 0; t < 32; ++t) {
        __syncthreads();
        *(frag_t*)&ks_s[srow_k * 72 + sseg_k * 8] = kreg;
        *(frag_t*)&vt_s[srow_v * 40 + sseg_v * 8] = vreg;
        if (tid < 8) *(float4*)&diag_s[tid * 4] = dreg;
        __syncthreads();
        if (t < 31) {
            kreg = *(const frag_t*)(kb + kbase + (size_t)(t + 1) * 2048);
            vreg = *(const frag_t*)(vT + vbase + (size_t)(t + 1) * 32);
            if (tid < 8) dreg = *(const float4*)(dgp + (t + 1) * 32 + tid * 4);
        }

        f32x4 sa[2];
        sa[0] = (f32x4){0.f, 0.f, 0.f, 0.f};
        sa[1] = (f32x4){0.f, 0.f, 0.f, 0.f};
#pragma unroll
        for (int s = 0; s < 2; ++s) {
            frag_t a = *(const frag_t*)&ks_s[(tn * 16 + m16) * 72 + s * 32 + q * 8];
#pragma unroll
            for (int jj = 0; jj < 2; ++jj) {
                const ushort* prow = &pj_s[((tmb + jj) * 16 + m16) * 136 + s * 32 + q * 8];
                frag_t bhi = *(const frag_t*)prow;
                frag_t blo = *(const frag_t*)(prow + 64);
                sa[jj] = __builtin_amdgcn_mfma_f32_16x16x32_bf16(a, bhi, sa[jj], 0, 0, 0);
                sa[jj] = __builtin_amdgcn_mfma_f32_16x16x32_bf16(a, blo, sa[jj], 0, 0, 0);
            }
        }

#pragma unroll
        for (int jj = 0; jj < 2; ++jj) {
            int m_l = (tmb + jj) * 16 + m16;
            bool valid = (m0 + m_l) < Mm;
            sh4 pk;
            float vsum = 0.f;
#pragma unroll
            for (int r = 0; r < 4; ++r) {
                int n_l = tn * 16 + q * 4 + r;
                float val = valid ? RATIO * (__expf(sa[jj][r] - diag_s[n_l] - kst) + EPS_FAVOR) : 0.f;
                ushort hb = f2bf(val);
                pk[r] = (short)hb;
                vsum += bf2f(hb);
            }
            ksacc[jj] += vsum;
            *(sh4*)&kf_s[m_l * 40 + tn * 16 + q * 4] = pk;
        }
        __syncthreads();

        {
            frag_t a = *(const frag_t*)&kf_s[(w * 16 + m16) * 40 + q * 8];
#pragma unroll
            for (int j = 0; j < 4; ++j) {
                frag_t b = *(const frag_t*)&vt_s[(j * 16 + m16) * 40 + q * 8];
                acc_c[j] = __builtin_amdgcn_mfma_f32_16x16x32_bf16(a, b, acc_c[j], 0, 0, 0);
            }
        }
    }

#pragma unroll
    for (int j = 0; j < 4; ++j)
#pragma unroll
        for (int r = 0; r < 4; ++r) {
            int m = m0 + w * 16 + q * 4 + r;
            if (m < Mm)
                atomicAdd(&ctx[((size_t)bh * Mm + m) * 64 + j * 16 + m16], acc_c[j][r]);
        }
#pragma unroll
    for (int jj = 0; jj < 2; ++jj) {
        float v = ksacc[jj];
        v += __shfl_xor(v, 16);
        v += __shfl_xor(v, 32);
        int m = m0 + (tmb + jj) * 16 + m16;
        if (q == 0 && m < Mm) atomicAdd(&ksum[(size_t)bh * Mm + m], v);
    }
}

// ---------------------------------------------------------------------------
// q-side via MFMA v3 (verified R7): unified 10-chunk T14 pipeline
// ---------------------------------------------------------------------------
__global__ __launch_bounds__(256, 3) void qout_mfma_kernel(
    const ushort* __restrict__ qb, const ushort* __restrict__ pb,
    const ushort* __restrict__ cT, const float* __restrict__ ksum,
    ushort* __restrict__ attnb)
{
    const int n0 = blockIdx.x * 64;
    const int bh = blockIdx.y;
    const int b = bh >> 4, h = bh & 15;
    const int tid = threadIdx.x;
    const int lane = tid & 63, w = tid >> 6;
    const int q = lane >> 4, m16 = lane & 15;

    __shared__ ushort qs_s[64 * 64];        //  8.0 KB (linear, gld16-staged)
    __shared__ ushort pj_s[2 * 64 * 136];   // 34.0 KB ring
    __shared__ ushort qf_s[64 * 72];        //  9.0 KB chunk buffer
    __shared__ float  diag_s[64];
    __shared__ float  ksum_s[320];

    const ushort* cbase = cT + (size_t)bh * 40960;

#define LOADCH(i_) {                                                              \
        for (int t_ = 0; t_ < 4; ++t_) {                                          \
            int idx_ = tid + t_ * 256, rr_ = idx_ >> 4, cc_ = idx_ & 15;          \
            g[t_] = ((i_) <= 4)                                                   \
                ? *(const frag_t*)(pb + (size_t)((i_) * 64 + rr_) * 128 + cc_ * 8)\
                : *(const frag_t*)(cbase + (size_t)rr_ * 640 + (cc_ >> 3) * 320   \
                                   + ((i_) - 5) * 64 + (cc_ & 7) * 8);            \
        } }
#define STORECH(i_) {                                                             \
        ushort* sl_ = pj_s + (((i_) & 1) * 8704);                                 \
        for (int t_ = 0; t_ < 4; ++t_) {                                          \
            int idx_ = tid + t_ * 256, rr_ = idx_ >> 4, cc_ = idx_ & 15;          \
            *(frag_t*)&sl_[rr_ * 136 + cc_ * 8] = g[t_];                          \
        } }

    for (int m = tid; m < 320; m += 256)
        ksum_s[m] = (m < Mm) ? ksum[(size_t)bh * Mm + m] : 0.f;

    const ushort* qsrc = qb + ((size_t)bh * Nn + n0) * 64;
    gld16(qsrc + tid * 8,        (void*)(qs_s + tid * 8));
    gld16(qsrc + 2048 + tid * 8, (void*)(qs_s + 2048 + tid * 8));

    frag_t g[4];
    LOADCH(0);
    STORECH(0);
    LOADCH(1);
    asm volatile("s_waitcnt vmcnt(4)" ::: "memory");
    __builtin_amdgcn_sched_barrier(0);
    SYNC_LDS();

    if (tid < 64) {
        float s = 0.f;
#pragma unroll 8
        for (int k = 0; k < 64; ++k) { float f = bf2f(qs_s[tid * 64 + k]); s += f * f; }
        diag_s[tid] = 0.5f * s;
    }
    frag_t aq[2];
#pragma unroll
    for (int s = 0; s < 2; ++s)
        aq[s] = *(const frag_t*)&qs_s[(w * 16 + m16) * 64 + s * 32 + q * 8];
    SYNC_LDS();

    f32x4 sA[20];
#pragma unroll
    for (int t = 0; t < 20; ++t) sA[t] = (f32x4){0.f, 0.f, 0.f, 0.f};

#pragma unroll
    for (int mc = 0; mc < 5; ++mc) {
        const ushort* sl = pj_s + ((mc & 1) * 8704);
        __builtin_amdgcn_s_setprio(1);
#pragma unroll
        for (int tm = 0; tm < 4; ++tm)
#pragma unroll
            for (int s = 0; s < 2; ++s) {
                const ushort* pr = &sl[(tm * 16 + m16) * 136 + s * 32 + q * 8];
                frag_t bhi = *(const frag_t*)pr;
                frag_t blo = *(const frag_t*)(pr + 64);
                sA[mc * 4 + tm] = __builtin_amdgcn_mfma_f32_16x16x32_bf16(aq[s], bhi, sA[mc * 4 + tm], 0, 0, 0);
                sA[mc * 4 + tm] = __builtin_amdgcn_mfma_f32_16x16x32_bf16(aq[s], blo, sA[mc * 4 + tm], 0, 0, 0);
            }
        __builtin_amdgcn_s_setprio(0);
        STORECH(mc + 1);
        LOADCH(mc + 2);
        SYNC_LDS();
    }

    float mx[4] = {-3.0e38f, -3.0e38f, -3.0e38f, -3.0e38f};
#pragma unroll
    for (int t = 0; t < 17; ++t) {
        bool v = (t < 16) || (m16 < 10);
        if (v) {
#pragma unroll
            for (int r = 0; r < 4; ++r) mx[r] = fmaxf(mx[r], sA[t][r]);
        }
    }
#pragma unroll
    for (int r = 0; r < 4; ++r) {
        float v = mx[r];
        v = fmaxf(v, __shfl_xor(v, 1));
        v = fmaxf(v, __shfl_xor(v, 2));
        v = fmaxf(v, __shfl_xor(v, 4));
        v = fmaxf(v, __shfl_xor(v, 8));
        mx[r] = v;
    }
    float dg[4];
#pragma unroll
    for (int r = 0; r < 4; ++r) dg[r] = diag_s[w * 16 + q * 4 + r];

    float ds[4] = {0.f, 0.f, 0.f, 0.f};
    f32x4 oA[4];
#pragma unroll
    for (int dt = 0; dt < 4; ++dt) oA[dt] = (f32x4){0.f, 0.f, 0.f, 0.f};

#pragma unroll
    for (int mc = 0; mc < 5; ++mc) {
#pragma unroll
        for (int tm = 0; tm < 4; ++tm) {
            int t = mc * 4 + tm;
            float ksm = ksum_s[t * 16 + m16];
#pragma unroll
            for (int r = 0; r < 4; ++r) {
                ushort hb = f2bf(RATIO * (__expf(sA[t][r] - dg[r] - mx[r]) + EPS_FAVOR));
                ds[r] += bf2f(hb) * ksm;
                qf_s[(w * 16 + q * 4 + r) * 72 + tm * 16 + m16] = hb;
            }
        }
        const ushort* sl = pj_s + (((mc + 5) & 1) * 8704);
        __builtin_amdgcn_s_setprio(1);
#pragma unroll
        for (int s = 0; s < 2; ++s) {
            frag_t a = *(const frag_t*)&qf_s[(w * 16 + m16) * 72 + s * 32 + q * 8];
#pragma unroll
            for (int dt = 0; dt < 4; ++dt) {
                const ushort* pr = &sl[(dt * 16 + m16) * 136 + s * 32 + q * 8];
                frag_t bhi = *(const frag_t*)pr;
                frag_t blo = *(const frag_t*)(pr + 64);
                oA[dt] = __builtin_amdgcn_mfma_f32_16x16x32_bf16(a, bhi, oA[dt], 0, 0, 0);
                oA[dt] = __builtin_amdgcn_mfma_f32_16x16x32_bf16(a, blo, oA[dt], 0, 0, 0);
            }
        }
        __builtin_amdgcn_s_setprio(0);
        if (mc + 6 <= 9) STORECH(mc + 6);
        if (mc + 7 <= 9) LOADCH(mc + 7);
        SYNC_LDS();
    }
#undef LOADCH
#undef STORECH

#pragma unroll
    for (int r = 0; r < 4; ++r) {
        float v = ds[r];
        v += __shfl_xor(v, 1);
        v += __shfl_xor(v, 2);
        v += __shfl_xor(v, 4);
        v += __shfl_xor(v, 8);
        ds[r] = 1.0f / v;
    }
#pragma unroll
    for (int dt = 0; dt < 4; ++dt)
#pragma unroll
        for (int r = 0; r < 4; ++r) {
            int n = n0 + w * 16 + q * 4 + r;
            attnb[((size_t)(b * Nn + n)) * Dd + h * 64 + dt * 16 + m16] =
                f2bf(oA[dt][r] * ds[r]);
        }
}

// ---------------------------------------------------------------------------
// LayerNorm: one block per row of 1024
// ---------------------------------------------------------------------------
__global__ __launch_bounds__(256) void ln_kernel(
    const float* __restrict__ y, const float* __restrict__ gamma,
    const float* __restrict__ beta, float* __restrict__ out)
{
    const int row = blockIdx.x;
    const int tid = threadIdx.x;
    float4 v = *(const float4*)(y + (size_t)row * Dd + tid * 4);
    float s = v.x + v.y + v.z + v.w;
    float q = v.x * v.x + v.y * v.y + v.z * v.z + v.w * v.w;
    __shared__ float rs[256], rq[256];
    rs[tid] = s; rq[tid] = q;
    __syncthreads();
    for (int off = 128; off > 0; off >>= 1) {
        if (tid < off) { rs[tid] += rs[tid + off]; rq[tid] += rq[tid + off]; }
        __syncthreads();
    }
    float mu = rs[0] * (1.0f / Dd);
    float var = rq[0] * (1.0f / Dd) - mu * mu;
    float rstd = rsqrtf(var + EPS_LN);
    float4 gm = *(const float4*)(gamma + tid * 4);
    float4 bt = *(const float4*)(beta + tid * 4);
    float4 o;
    o.x = (v.x - mu) * rstd * gm.x + bt.x;
    o.y = (v.y - mu) * rstd * gm.y + bt.y;
    o.z = (v.z - mu) * rstd * gm.z + bt.z;
    o.w = (v.w - mu) * rstd * gm.w + bt.w;
    *(float4*)(out + (size_t)row * Dd + tid * 4) = o;
}

// ---------------------------------------------------------------------------
extern "C" void kernel_launch(void* const* d_in, const int* in_sizes, int n_in,
                              void* d_out, int out_size, void* d_ws, size_t ws_size,
                              hipStream_t stream) {
    const float* x     = (const float*)d_in[0];
    const float* Wq    = (const float*)d_in[1];
    const float* Wk    = (const float*)d_in[2];
    const float* Wv    = (const float*)d_in[3];
    const float* Wo    = (const float*)d_in[4];
    const float* bo    = (const float*)d_in[5];
    const float* proj  = (const float*)d_in[6];
    const float* gamma = (const float*)d_in[7];
    const float* beta  = (const float*)d_in[8];
    float* out = (float*)d_out;

    const size_t TS = 16777216;           // tokens(16384) * 1024
    ushort* xb  = (ushort*)d_ws;          // x bf16; reused as attnb after QKV gemm
    ushort* qb  = xb + TS;
    ushort* kb  = qb + TS;
    ushort* vb  = kb + TS;                // holds vT [bh][64][4096] (gemm z==2 writes)
    ushort* WTq = vb + TS;
    ushort* WTk = WTq + 1048576;
    ushort* WTv = WTk + 1048576;
    ushort* WTo = WTv + 1048576;
    float*  ctx  = (float*)(WTo + 1048576);         // BH*M*64 fp32
    float*  ksum = ctx + (size_t)BHh * Mm * DHh;    // BH*M
    unsigned* stab = (unsigned*)(ksum + (size_t)BHh * Mm);
    ushort* attnb = xb;                   // token-major bf16 attn (after gemm consumed xb)
    float*  yres  = (float*)qb;           // fp32, overlays qb+kb after qout
    ushort* vT     = vb;                  // [bh][64][4096] bf16, direct from gemm z==2
    float*  diagk  = (float*)WTq;         // 1 MB in the 2 MB WTq slot (after gemm)
    ushort* projb2 = WTk;                 // 80 KB in the 2 MB WTk slot (after gemm)
    ushort* ctxT   = vb;                  // [bh][64][640] bf16 hi|lo (after ctx consumed vT)

    hipMemsetAsync(ctx, 0, (size_t)BHh * Mm * DHh * sizeof(float), stream);
    hipMemsetAsync(ksum, 0, (size_t)BHh * Mm * sizeof(float), stream);
    hipMemsetAsync(stab, 0, BHh * sizeof(unsigned), stream);

    conv_x_kernel<<<8192, 256, 0, stream>>>(x, xb);
    conv_wt_kernel<<<dim3(16, 16, 4), 256, 0, stream>>>(Wq, Wk, Wv, Wo, WTq, WTk, WTv, WTo);

    gemm256<<<dim3(64, 4, 3), 512, 0, stream>>>(xb, WTq, WTk, WTv, qb, kb, vT,
                                                nullptr, nullptr, nullptr, 0);

    diag_kernel<<<1024, 256, 0, stream>>>(kb, diagk);
    conv_proj_kernel<<<80, 256, 0, stream>>>(proj, projb2);

    kstab_mfma_kernel<<<dim3(Nn / 256, BHh), 256, 0, stream>>>(kb, projb2, stab);

    ctx_mfma_kernel<<<dim3(5, 4, BHh), 256, 0, stream>>>(kb, vT, projb2, diagk, stab,
                                                         ctx, ksum);

    ctx2bt_kernel<<<dim3(5, BHh), 256, 0, stream>>>(ctx, ctxT);

    qout_mfma_kernel<<<dim3(Nn / 64, BHh), 256, 0, stream>>>(qb, projb2, ctxT, ksum, attnb);

    gemm256<<<dim3(64, 4, 1), 512, 0, stream>>>(attnb, WTo, nullptr, nullptr,
                                                nullptr, nullptr, nullptr, bo, x, yres, 1);
    ln_kernel<<<16384, 256, 0, stream>>>(yres, gamma, beta, out);
}